// Round 7
// baseline (1806.028 us; speedup 1.0000x reference)
//
#include <hip/hip_runtime.h>
#include <hip/hip_bf16.h>
#include <stdint.h>

#define SEQ   2048
#define DIM   1024
#define NST   64
#define DI    2048
#define DTR   64
#define ROWS  8192   // BATCH*SEQ

typedef __hip_bfloat16 bf16;
typedef __attribute__((ext_vector_type(8))) short short8;   // 8 bf16 = 4 VGPRs
typedef __attribute__((ext_vector_type(4))) short bs4x;     // 4 bf16 = 2 VGPRs
typedef __attribute__((ext_vector_type(4))) float f32x4;

typedef const __attribute__((address_space(1))) void gv_t;  // global
typedef __attribute__((address_space(3))) void lv_t;        // LDS

__device__ __forceinline__ float bs2f(short s) {
    return __uint_as_float(((uint32_t)(uint16_t)s) << 16);
}
__device__ __forceinline__ short f2bs(float f) {
    bf16 h = __float2bfloat16(f);
    return *(short*)&h;
}
__device__ __forceinline__ float b2f(bf16 v) { return __bfloat162float(v); }

// ------- transpose f32 -> bf16 with optional zero-pad: out[n][k] = in[k][n] --
__global__ __launch_bounds__(256) void transpose_pad(
    const float* __restrict__ in, bf16* __restrict__ out,
    int Kdim, int lgK, int Nin, int total)
{
    int idx = blockIdx.x * 256 + threadIdx.x;
    if (idx >= total) return;
    int n = idx >> lgK;
    int k = idx & (Kdim - 1);
    float v = (n < Nin) ? in[(size_t)k * Nin + n] : 0.f;
    out[idx] = __float2bfloat16(v);
}

// ---------------- LayerNorm: one wave per 1024-wide f32 row -> bf16 ---------
__global__ __launch_bounds__(256) void ln_kernel(
    const float* __restrict__ x, const float* __restrict__ w,
    const float* __restrict__ b, bf16* __restrict__ xn)
{
    int row  = blockIdx.x * 4 + (threadIdx.x >> 6);
    int lane = threadIdx.x & 63;
    const float4* xr = (const float4*)(x + (size_t)row * DIM);
    float4 v[4];
    float s = 0.f, s2 = 0.f;
#pragma unroll
    for (int q = 0; q < 4; ++q) {
        v[q] = xr[q * 64 + lane];
        s  += v[q].x + v[q].y + v[q].z + v[q].w;
        s2 += v[q].x*v[q].x + v[q].y*v[q].y + v[q].z*v[q].z + v[q].w*v[q].w;
    }
#pragma unroll
    for (int off = 32; off; off >>= 1) {
        s  += __shfl_xor(s, off);
        s2 += __shfl_xor(s2, off);
    }
    float mu  = s * (1.f / DIM);
    float var = s2 * (1.f / DIM) - mu * mu;
    float rs  = rsqrtf(var + 1e-5f);
    const float4* wp = (const float4*)w;
    const float4* bp = (const float4*)b;
#pragma unroll
    for (int q = 0; q < 4; ++q) {
        float4 wv = wp[q * 64 + lane];
        float4 bv = bp[q * 64 + lane];
        bs4x o;
        o[0] = f2bs((v[q].x - mu) * rs * wv.x + bv.x);
        o[1] = f2bs((v[q].y - mu) * rs * wv.y + bv.y);
        o[2] = f2bs((v[q].z - mu) * rs * wv.z + bv.z);
        o[3] = f2bs((v[q].w - mu) * rs * wv.w + bv.w);
        *(bs4x*)(xn + (size_t)row * DIM + (q * 64 + lane) * 4) = o;
    }
}

// ---------------- 128x128 BK=32 MFMA bf16 GEMM, Bt = [N][K] ----------------
// MODE 0: store bf16 (predicated col<nvalid). MODE 1: softplus(acc+bias[n]) bf16.
// MODE 2: acc + residual[m][n] (f32), store FLOAT (final output).
template<int MODE>
__global__ __launch_bounds__(256) void gemm_bt(
    const bf16* __restrict__ A, int lda,
    const bf16* __restrict__ Bt, int ldb, int K,
    bf16* __restrict__ outp, float* __restrict__ outF, int ldo, int nvalid,
    const float* __restrict__ aux)
{
    __shared__ alignas(16) bf16 As[128 * 32];
    __shared__ alignas(16) bf16 Bs[128 * 32];
    const int tid = threadIdx.x;
    const int wid = tid >> 6, lane = tid & 63;
    const int m0 = blockIdx.x * 128, n0 = blockIdx.y * 128;
    const int wr = wid >> 1, wc = wid & 1;

    f32x4 acc[4][4];
#pragma unroll
    for (int i = 0; i < 4; ++i)
#pragma unroll
        for (int j = 0; j < 4; ++j) acc[i][j] = (f32x4){0.f, 0.f, 0.f, 0.f};

    const int srow = tid >> 2;           // 0..63
    const int scol = (tid & 3) * 8;      // 0,8,16,24
    const bf16* ga = A  + (size_t)(m0 + srow) * lda + scol;
    const bf16* gb = Bt + (size_t)(n0 + srow) * ldb + scol;
    char* lA0 = (char*)As + wid * 1024;
    char* lA1 = (char*)As + 4096 + wid * 1024;
    char* lB0 = (char*)Bs + wid * 1024;
    char* lB1 = (char*)Bs + 4096 + wid * 1024;

    const int frow = lane & 15;
    const int fk   = (lane >> 4) * 8;

    for (int k0 = 0; k0 < K; k0 += 32) {
        __builtin_amdgcn_global_load_lds((gv_t*)(ga + k0),                      (lv_t*)lA0, 16, 0, 0);
        __builtin_amdgcn_global_load_lds((gv_t*)(ga + (size_t)64 * lda + k0),   (lv_t*)lA1, 16, 0, 0);
        __builtin_amdgcn_global_load_lds((gv_t*)(gb + k0),                      (lv_t*)lB0, 16, 0, 0);
        __builtin_amdgcn_global_load_lds((gv_t*)(gb + (size_t)64 * ldb + k0),   (lv_t*)lB1, 16, 0, 0);
        __syncthreads();
        short8 af[4], bf_[4];
#pragma unroll
        for (int i = 0; i < 4; ++i) {
            af[i]  = *(const short8*)((const char*)As + ((wr*64 + i*16 + frow) * 32 + fk) * 2);
            bf_[i] = *(const short8*)((const char*)Bs + ((wc*64 + i*16 + frow) * 32 + fk) * 2);
        }
#pragma unroll
        for (int i = 0; i < 4; ++i)
#pragma unroll
            for (int j = 0; j < 4; ++j)
                acc[i][j] = __builtin_amdgcn_mfma_f32_16x16x32_bf16(af[i], bf_[j], acc[i][j], 0, 0, 0);
        __syncthreads();
    }

    const int erow = wr * 64 + (lane >> 4) * 4;
    const int ecol = wc * 64 + (lane & 15);
#pragma unroll
    for (int i = 0; i < 4; ++i)
#pragma unroll
        for (int j = 0; j < 4; ++j)
#pragma unroll
            for (int r = 0; r < 4; ++r) {
                int gr = m0 + erow + i * 16 + r;
                int gc = n0 + ecol + j * 16;
                float v = acc[i][j][r];
                if (MODE == 0) {
                    if (gc < nvalid) outp[(size_t)gr * ldo + gc] = __float2bfloat16(v);
                } else if (MODE == 1) {
                    v += aux[gc];
                    float sp = fmaxf(v, 0.f) + log1pf(__expf(-fabsf(v)));
                    outp[(size_t)gr * ldo + gc] = __float2bfloat16(sp);
                } else {
                    v += aux[(size_t)gr * ldo + gc];
                    outF[(size_t)gr * ldo + gc] = v;      // f32 final output
                }
            }
}

// ---------------- depthwise causal conv (DCONV=4) + SiLU -------------------
__global__ __launch_bounds__(256) void conv_silu_kernel(
    const bf16* __restrict__ uz, const float* __restrict__ cw,
    const float* __restrict__ cb, bf16* __restrict__ uc)
{
    int row = blockIdx.x;                 // 0..8191  (b*SEQ + t)
    int d8  = threadIdx.x * 8;            // channel group base
    int t   = row & (SEQ - 1);
    float accv[8];
    float4 cb0 = *(const float4*)(cb + d8);
    float4 cb1 = *(const float4*)(cb + d8 + 4);
    accv[0]=cb0.x; accv[1]=cb0.y; accv[2]=cb0.z; accv[3]=cb0.w;
    accv[4]=cb1.x; accv[5]=cb1.y; accv[6]=cb1.z; accv[7]=cb1.w;
    const float4* cw4 = (const float4*)cw;   // one float4 per channel (4 taps)
    float4 wj[8];
#pragma unroll
    for (int j = 0; j < 8; ++j) wj[j] = cw4[d8 + j];
#pragma unroll
    for (int k = 0; k < 4; ++k) {
        int tt = t + k - 3;
        if (tt < 0) continue;             // block-uniform predicate
        short8 uv = *(const short8*)(uz + (size_t)(row + k - 3) * 4096 + d8);
        float wk[8] = {((const float*)&wj[0])[k], ((const float*)&wj[1])[k],
                       ((const float*)&wj[2])[k], ((const float*)&wj[3])[k],
                       ((const float*)&wj[4])[k], ((const float*)&wj[5])[k],
                       ((const float*)&wj[6])[k], ((const float*)&wj[7])[k]};
#pragma unroll
        for (int j = 0; j < 8; ++j)
            accv[j] += bs2f(uv[j]) * wk[j];
    }
    short8 o;
#pragma unroll
    for (int j = 0; j < 8; ++j) {
        float v = accv[j];
        o[j] = f2bs(v / (1.f + __expf(-v)));
    }
    *(short8*)(uc + (size_t)row * DI + d8) = o;
}

// ---------------- selective scan: one wave per (b,d), lane = state n --------
__global__ __launch_bounds__(256) void scan_kernel(
    const bf16* __restrict__ dt, const bf16* __restrict__ proj,
    const bf16* __restrict__ uc, const float* __restrict__ A_log,
    bf16* __restrict__ ys)
{
    const int wid = threadIdx.x >> 6, lane = threadIdx.x & 63;
    const int b  = blockIdx.x >> 9;
    const int dg = blockIdx.x & 511;
    const int d  = dg * 4 + wid;
    __shared__ alignas(16) bf16 Bsh[64][64];
    __shared__ alignas(16) bf16 Csh[64][64];
    const float Aval = -__expf(A_log[d * NST + lane]);
    float h = 0.f;
    const int rowbase = b * SEQ;
    for (int t0 = 0; t0 < SEQ; t0 += 64) {
        __syncthreads();
        {   // stage B,C tiles: proj cols [64..128) and [128..192)
            int r  = threadIdx.x >> 2;
            int cs = (threadIdx.x & 3) * 16;
            const bf16* src = proj + (size_t)(rowbase + t0 + r) * 192 + DTR + cs;
            *(short8*)&Bsh[r][cs]     = *(const short8*)src;
            *(short8*)&Bsh[r][cs + 8] = *(const short8*)(src + 8);
            *(short8*)&Csh[r][cs]     = *(const short8*)(src + NST);
            *(short8*)&Csh[r][cs + 8] = *(const short8*)(src + NST + 8);
        }
        __syncthreads();
        for (int tt = 0; tt < 64; ++tt) {
            const size_t ro = (size_t)(rowbase + t0 + tt) * DI + d;
            float dtv = b2f(dt[ro]);                 // wave-uniform broadcast
            float uv  = b2f(uc[ro]);
            float Bv  = b2f(Bsh[tt][lane]);
            float Cv  = b2f(Csh[tt][lane]);
            float dA  = __expf(dtv * Aval);
            h = h * dA + dtv * uv * Bv;
            float p = h * Cv;
#pragma unroll
            for (int off = 32; off; off >>= 1) p += __shfl_xor(p, off);
            if (lane == 0) ys[ro] = __float2bfloat16(p);
        }
    }
}

// ---------------- gate/assemble: g = (ys + uc*D) * silu(z), in-place on uc --
__global__ __launch_bounds__(256) void assemble_kernel(
    const bf16* __restrict__ ys, const bf16* __restrict__ uz,
    const float* __restrict__ Dv, bf16* __restrict__ uc)
{
    int idx = blockIdx.x * 256 + threadIdx.x;   // over ROWS*DI/8
    int row = idx >> 8;
    int d8  = (idx & 255) * 8;
    short8 yv  = *(const short8*)(ys + (size_t)row * DI + d8);
    short8 ucv = *(const short8*)(uc + (size_t)row * DI + d8);
    short8 zv  = *(const short8*)(uz + (size_t)row * 4096 + DI + d8);
    float4 d0 = *(const float4*)(Dv + d8);
    float4 d1 = *(const float4*)(Dv + d8 + 4);
    float dv[8] = {d0.x, d0.y, d0.z, d0.w, d1.x, d1.y, d1.z, d1.w};
    short8 o;
#pragma unroll
    for (int j = 0; j < 8; ++j) {
        float z = bs2f(zv[j]);
        float g = (bs2f(yv[j]) + bs2f(ucv[j]) * dv[j]) * (z / (1.f + __expf(-z)));
        o[j] = f2bs(g);
    }
    *(short8*)(uc + (size_t)row * DI + d8) = o;
}

extern "C" void kernel_launch(void* const* d_in, const int* in_sizes, int n_in,
                              void* d_out, int out_size, void* d_ws, size_t ws_size,
                              hipStream_t stream) {
    const float* x    = (const float*)d_in[0];
    const float* lnw  = (const float*)d_in[1];
    const float* lnb  = (const float*)d_in[2];
    const float* Win  = (const float*)d_in[3];
    const float* cw   = (const float*)d_in[4];
    const float* cb   = (const float*)d_in[5];
    const float* Wxp  = (const float*)d_in[6];
    const float* Wdt  = (const float*)d_in[7];
    const float* bdt  = (const float*)d_in[8];
    const float* Alog = (const float*)d_in[9];
    const float* Dp   = (const float*)d_in[10];
    const float* Wout = (const float*)d_in[11];
    float* out = (float*)d_out;           // reference output dtype = float32

    char* ws = (char*)d_ws;               // ~201.6 MB used
    bf16* xn    = (bf16*)(ws + 0);                 // 8192x1024
    bf16* WtIn  = (bf16*)(ws + 16777216);          // 4096x1024
    bf16* WtXp  = (bf16*)(ws + 25165824);          // 256x2048 (zero-padded)
    bf16* WtDt  = (bf16*)(ws + 26214400);          // 2048x64
    bf16* WtOut = (bf16*)(ws + 26476544);          // 1024x2048
    bf16* uz    = (bf16*)(ws + 30670848);          // 8192x4096 (u | z)
    bf16* uc    = (bf16*)(ws + 97779712);          // 8192x2048 (later g, in place)
    bf16* proj  = (bf16*)(ws + 131334144);         // 8192x192
    bf16* dtb   = (bf16*)(ws + 134479872);         // 8192x2048
    bf16* ysb   = (bf16*)(ws + 168034304);         // 8192x2048

    // weight transposes (Bt layouts, k-contiguous rows), f32 -> bf16
    transpose_pad<<<16384, 256, 0, stream>>>(Win,  WtIn,  1024, 10, 4096, 4096 * 1024);
    transpose_pad<<<2048,  256, 0, stream>>>(Wxp,  WtXp,  2048, 11, 192,  256 * 2048);
    transpose_pad<<<512,   256, 0, stream>>>(Wdt,  WtDt,  64,   6,  2048, 2048 * 64);
    transpose_pad<<<8192,  256, 0, stream>>>(Wout, WtOut, 2048, 11, 1024, 1024 * 2048);

    ln_kernel<<<2048, 256, 0, stream>>>(x, lnw, lnb, xn);
    gemm_bt<0><<<dim3(64, 32), 256, 0, stream>>>(xn, 1024, WtIn, 1024, 1024,
                                                 uz, nullptr, 4096, 4096, nullptr);
    conv_silu_kernel<<<8192, 256, 0, stream>>>(uz, cw, cb, uc);
    gemm_bt<0><<<dim3(64, 2), 256, 0, stream>>>(uc, 2048, WtXp, 2048, 2048,
                                                proj, nullptr, 192, 192, nullptr);
    gemm_bt<1><<<dim3(64, 16), 256, 0, stream>>>(proj, 192, WtDt, 64, 64,
                                                 dtb, nullptr, 2048, 2048, bdt);
    scan_kernel<<<2048, 256, 0, stream>>>(dtb, proj, uc, Alog, ysb);
    assemble_kernel<<<8192, 256, 0, stream>>>(ysb, uz, Dp, uc);
    gemm_bt<2><<<dim3(64, 8), 256, 0, stream>>>(uc, 2048, WtOut, 2048, 2048,
                                                nullptr, out, 1024, 1024, x);
}

// Round 8
// 834.777 us; speedup vs baseline: 2.1635x; 2.1635x over previous
//
#include <hip/hip_runtime.h>
#include <hip/hip_bf16.h>
#include <stdint.h>

#define SEQ   2048
#define DIM   1024
#define NST   64
#define DI    2048
#define DTR   64
#define ROWS  8192   // BATCH*SEQ

typedef __hip_bfloat16 bf16;
typedef __attribute__((ext_vector_type(8))) short short8;   // 8 bf16 = 4 VGPRs
typedef __attribute__((ext_vector_type(4))) short bs4x;     // 4 bf16 = 2 VGPRs
typedef __attribute__((ext_vector_type(4))) float f32x4;

typedef const __attribute__((address_space(1))) void gv_t;  // global
typedef __attribute__((address_space(3))) void lv_t;        // LDS

__device__ __forceinline__ float bs2f(short s) {
    return __uint_as_float(((uint32_t)(uint16_t)s) << 16);
}
__device__ __forceinline__ float lo16f(uint32_t u) {
    return __uint_as_float(u << 16);
}
__device__ __forceinline__ float hi16f(uint32_t u) {
    return __uint_as_float(u & 0xffff0000u);
}
__device__ __forceinline__ short f2bs(float f) {
    bf16 h = __float2bfloat16(f);
    return *(short*)&h;
}
__device__ __forceinline__ float b2f(bf16 v) { return __bfloat162float(v); }

// ------- transpose f32 -> bf16 with optional zero-pad: out[n][k] = in[k][n] --
__global__ __launch_bounds__(256) void transpose_pad(
    const float* __restrict__ in, bf16* __restrict__ out,
    int Kdim, int lgK, int Nin, int total)
{
    int idx = blockIdx.x * 256 + threadIdx.x;
    if (idx >= total) return;
    int n = idx >> lgK;
    int k = idx & (Kdim - 1);
    float v = (n < Nin) ? in[(size_t)k * Nin + n] : 0.f;
    out[idx] = __float2bfloat16(v);
}

// ---------------- LayerNorm: one wave per 1024-wide f32 row -> bf16 ---------
__global__ __launch_bounds__(256) void ln_kernel(
    const float* __restrict__ x, const float* __restrict__ w,
    const float* __restrict__ b, bf16* __restrict__ xn)
{
    int row  = blockIdx.x * 4 + (threadIdx.x >> 6);
    int lane = threadIdx.x & 63;
    const float4* xr = (const float4*)(x + (size_t)row * DIM);
    float4 v[4];
    float s = 0.f, s2 = 0.f;
#pragma unroll
    for (int q = 0; q < 4; ++q) {
        v[q] = xr[q * 64 + lane];
        s  += v[q].x + v[q].y + v[q].z + v[q].w;
        s2 += v[q].x*v[q].x + v[q].y*v[q].y + v[q].z*v[q].z + v[q].w*v[q].w;
    }
#pragma unroll
    for (int off = 32; off; off >>= 1) {
        s  += __shfl_xor(s, off);
        s2 += __shfl_xor(s2, off);
    }
    float mu  = s * (1.f / DIM);
    float var = s2 * (1.f / DIM) - mu * mu;
    float rs  = rsqrtf(var + 1e-5f);
    const float4* wp = (const float4*)w;
    const float4* bp = (const float4*)b;
#pragma unroll
    for (int q = 0; q < 4; ++q) {
        float4 wv = wp[q * 64 + lane];
        float4 bv = bp[q * 64 + lane];
        bs4x o;
        o[0] = f2bs((v[q].x - mu) * rs * wv.x + bv.x);
        o[1] = f2bs((v[q].y - mu) * rs * wv.y + bv.y);
        o[2] = f2bs((v[q].z - mu) * rs * wv.z + bv.z);
        o[3] = f2bs((v[q].w - mu) * rs * wv.w + bv.w);
        *(bs4x*)(xn + (size_t)row * DIM + (q * 64 + lane) * 4) = o;
    }
}

// ---------------- 128x128 BK=32 MFMA bf16 GEMM, Bt = [N][K] ----------------
// MODE 0: store bf16 (predicated col<nvalid). MODE 1: softplus(acc+bias[n]) bf16.
// MODE 2: acc + residual[m][n] (f32), store FLOAT (final output).
template<int MODE>
__global__ __launch_bounds__(256) void gemm_bt(
    const bf16* __restrict__ A, int lda,
    const bf16* __restrict__ Bt, int ldb, int K,
    bf16* __restrict__ outp, float* __restrict__ outF, int ldo, int nvalid,
    const float* __restrict__ aux)
{
    __shared__ alignas(16) bf16 As[128 * 32];
    __shared__ alignas(16) bf16 Bs[128 * 32];
    const int tid = threadIdx.x;
    const int wid = tid >> 6, lane = tid & 63;
    const int m0 = blockIdx.x * 128, n0 = blockIdx.y * 128;
    const int wr = wid >> 1, wc = wid & 1;

    f32x4 acc[4][4];
#pragma unroll
    for (int i = 0; i < 4; ++i)
#pragma unroll
        for (int j = 0; j < 4; ++j) acc[i][j] = (f32x4){0.f, 0.f, 0.f, 0.f};

    const int srow = tid >> 2;           // 0..63
    const int scol = (tid & 3) * 8;      // 0,8,16,24
    const bf16* ga = A  + (size_t)(m0 + srow) * lda + scol;
    const bf16* gb = Bt + (size_t)(n0 + srow) * ldb + scol;
    char* lA0 = (char*)As + wid * 1024;
    char* lA1 = (char*)As + 4096 + wid * 1024;
    char* lB0 = (char*)Bs + wid * 1024;
    char* lB1 = (char*)Bs + 4096 + wid * 1024;

    const int frow = lane & 15;
    const int fk   = (lane >> 4) * 8;

    for (int k0 = 0; k0 < K; k0 += 32) {
        __builtin_amdgcn_global_load_lds((gv_t*)(ga + k0),                      (lv_t*)lA0, 16, 0, 0);
        __builtin_amdgcn_global_load_lds((gv_t*)(ga + (size_t)64 * lda + k0),   (lv_t*)lA1, 16, 0, 0);
        __builtin_amdgcn_global_load_lds((gv_t*)(gb + k0),                      (lv_t*)lB0, 16, 0, 0);
        __builtin_amdgcn_global_load_lds((gv_t*)(gb + (size_t)64 * ldb + k0),   (lv_t*)lB1, 16, 0, 0);
        __syncthreads();
        short8 af[4], bf_[4];
#pragma unroll
        for (int i = 0; i < 4; ++i) {
            af[i]  = *(const short8*)((const char*)As + ((wr*64 + i*16 + frow) * 32 + fk) * 2);
            bf_[i] = *(const short8*)((const char*)Bs + ((wc*64 + i*16 + frow) * 32 + fk) * 2);
        }
#pragma unroll
        for (int i = 0; i < 4; ++i)
#pragma unroll
            for (int j = 0; j < 4; ++j)
                acc[i][j] = __builtin_amdgcn_mfma_f32_16x16x32_bf16(af[i], bf_[j], acc[i][j], 0, 0, 0);
        __syncthreads();
    }

    const int erow = wr * 64 + (lane >> 4) * 4;
    const int ecol = wc * 64 + (lane & 15);
#pragma unroll
    for (int i = 0; i < 4; ++i)
#pragma unroll
        for (int j = 0; j < 4; ++j)
#pragma unroll
            for (int r = 0; r < 4; ++r) {
                int gr = m0 + erow + i * 16 + r;
                int gc = n0 + ecol + j * 16;
                float v = acc[i][j][r];
                if (MODE == 0) {
                    if (gc < nvalid) outp[(size_t)gr * ldo + gc] = __float2bfloat16(v);
                } else if (MODE == 1) {
                    v += aux[gc];
                    float sp = fmaxf(v, 0.f) + log1pf(__expf(-fabsf(v)));
                    outp[(size_t)gr * ldo + gc] = __float2bfloat16(sp);
                } else {
                    v += aux[(size_t)gr * ldo + gc];
                    outF[(size_t)gr * ldo + gc] = v;      // f32 final output
                }
            }
}

// ---------------- depthwise causal conv (DCONV=4) + SiLU -------------------
__global__ __launch_bounds__(256) void conv_silu_kernel(
    const bf16* __restrict__ uz, const float* __restrict__ cw,
    const float* __restrict__ cb, bf16* __restrict__ uc)
{
    int row = blockIdx.x;                 // 0..8191  (b*SEQ + t)
    int d8  = threadIdx.x * 8;            // channel group base
    int t   = row & (SEQ - 1);
    float accv[8];
    float4 cb0 = *(const float4*)(cb + d8);
    float4 cb1 = *(const float4*)(cb + d8 + 4);
    accv[0]=cb0.x; accv[1]=cb0.y; accv[2]=cb0.z; accv[3]=cb0.w;
    accv[4]=cb1.x; accv[5]=cb1.y; accv[6]=cb1.z; accv[7]=cb1.w;
    const float4* cw4 = (const float4*)cw;   // one float4 per channel (4 taps)
    float4 wj[8];
#pragma unroll
    for (int j = 0; j < 8; ++j) wj[j] = cw4[d8 + j];
#pragma unroll
    for (int k = 0; k < 4; ++k) {
        int tt = t + k - 3;
        if (tt < 0) continue;             // block-uniform predicate
        short8 uv = *(const short8*)(uz + (size_t)(row + k - 3) * 4096 + d8);
        float wk[8] = {((const float*)&wj[0])[k], ((const float*)&wj[1])[k],
                       ((const float*)&wj[2])[k], ((const float*)&wj[3])[k],
                       ((const float*)&wj[4])[k], ((const float*)&wj[5])[k],
                       ((const float*)&wj[6])[k], ((const float*)&wj[7])[k]};
#pragma unroll
        for (int j = 0; j < 8; ++j)
            accv[j] += bs2f(uv[j]) * wk[j];
    }
    short8 o;
#pragma unroll
    for (int j = 0; j < 8; ++j) {
        float v = accv[j];
        o[j] = f2bs(v / (1.f + __expf(-v)));
    }
    *(short8*)(uc + (size_t)row * DI + d8) = o;
}

// ---------------- selective scan v2: one wave per (b,d), lane = state n -----
// Per 64-step tile: stage packed (B,C) [t][n] and packed (dt,u) [d][t] in LDS.
// Inner step: 2 ds_read_b32 + 1 ds_write_b16 + ~11 VALU, no VMEM, no shuffles.
// Reduce: lane t row-sums wave-private P tile, one scattered store per tile.
__global__ __launch_bounds__(256) void scan_kernel(
    const bf16* __restrict__ dt, const bf16* __restrict__ proj,
    const bf16* __restrict__ uc, const float* __restrict__ A_log,
    bf16* __restrict__ ys)
{
    const int tid  = threadIdx.x;
    const int wid  = tid >> 6, lane = tid & 63;
    const int b    = blockIdx.x >> 9;
    const int dg   = blockIdx.x & 511;
    const int d    = dg * 4 + wid;
    const int rowbase = b * SEQ;

    __shared__ uint32_t BC[64][66];               // (B | C<<16) per [t][n], padded
    __shared__ uint32_t DTU[4][64];               // (dt | u<<16) per [wid][t]
    __shared__ alignas(16) short Pl[4][64 * 68];  // per-wave P[t][n], row stride 68

    const float Aval = -__expf(A_log[d * NST + lane]);
    float h = 0.f;

    // staging indices
    const int sr = tid >> 2;                 // 0..63 (t row for BC)
    const int sc = (tid & 3) * 16;           // 0,16,32,48 (n col group)
    const int st = tid >> 2;                 // t for DTU
    const int sw = tid & 3;                  // wid for DTU
    const int sd = dg * 4 + sw;

    short* const prow_w = &Pl[wid][lane];    // write base: + tt*68
    const short* const prow_r = &Pl[wid][lane * 68];  // read base (lane = t)

    for (int t0 = 0; t0 < SEQ; t0 += 64) {
        __syncthreads();   // previous tile fully consumed
        {   // stage BC: thread (sr, sc) packs 16 (B,C) pairs
            const bf16* src = proj + (size_t)(rowbase + t0 + sr) * 192 + DTR + sc;
            short8 B0 = *(const short8*)src;
            short8 B1 = *(const short8*)(src + 8);
            short8 C0 = *(const short8*)(src + NST);
            short8 C1 = *(const short8*)(src + NST + 8);
#pragma unroll
            for (int j = 0; j < 8; j += 2) {
                uint2 p0, p1;
                p0.x = (uint16_t)B0[j]     | ((uint32_t)(uint16_t)C0[j]     << 16);
                p0.y = (uint16_t)B0[j + 1] | ((uint32_t)(uint16_t)C0[j + 1] << 16);
                p1.x = (uint16_t)B1[j]     | ((uint32_t)(uint16_t)C1[j]     << 16);
                p1.y = (uint16_t)B1[j + 1] | ((uint32_t)(uint16_t)C1[j + 1] << 16);
                *(uint2*)&BC[sr][sc + j]     = p0;
                *(uint2*)&BC[sr][sc + 8 + j] = p1;
            }
            // stage DTU: thread (st, sw)
            size_t ro = (size_t)(rowbase + t0 + st) * DI + sd;
            DTU[sw][st] = *(const uint16_t*)&dt[ro]
                        | ((uint32_t)*(const uint16_t*)&uc[ro] << 16);
        }
        __syncthreads();

        // 64 steps, fully unrolled in groups of 16 (const LDS offsets)
#pragma unroll
        for (int tg = 0; tg < 4; ++tg) {
#pragma unroll
            for (int j = 0; j < 16; ++j) {
                const int tt = tg * 16 + j;
                uint32_t bc = BC[tt][lane];
                uint32_t du = DTU[wid][tt];
                float Bv  = lo16f(bc);
                float Cv  = hi16f(bc);
                float dtv = lo16f(du);
                float uv  = hi16f(du);
                float dA  = __expf(dtv * Aval);
                h = fmaf(h, dA, dtv * uv * Bv);
                prow_w[tt * 68] = f2bs(h * Cv);
            }
        }

        // row-reduce P: lane tt sums its 64 products (same-wave LDS dep)
        float ysum = 0.f;
#pragma unroll
        for (int j = 0; j < 16; ++j) {
            uint2 v = *(const uint2*)(prow_r + j * 4);
            ysum += lo16f(v.x) + hi16f(v.x) + lo16f(v.y) + hi16f(v.y);
        }
        ys[(size_t)(rowbase + t0 + lane) * DI + d] = __float2bfloat16(ysum);
    }
}

// ---------------- gate/assemble: g = (ys + uc*D) * silu(z), in-place on uc --
__global__ __launch_bounds__(256) void assemble_kernel(
    const bf16* __restrict__ ys, const bf16* __restrict__ uz,
    const float* __restrict__ Dv, bf16* __restrict__ uc)
{
    int idx = blockIdx.x * 256 + threadIdx.x;   // over ROWS*DI/8
    int row = idx >> 8;
    int d8  = (idx & 255) * 8;
    short8 yv  = *(const short8*)(ys + (size_t)row * DI + d8);
    short8 ucv = *(const short8*)(uc + (size_t)row * DI + d8);
    short8 zv  = *(const short8*)(uz + (size_t)row * 4096 + DI + d8);
    float4 d0 = *(const float4*)(Dv + d8);
    float4 d1 = *(const float4*)(Dv + d8 + 4);
    float dv[8] = {d0.x, d0.y, d0.z, d0.w, d1.x, d1.y, d1.z, d1.w};
    short8 o;
#pragma unroll
    for (int j = 0; j < 8; ++j) {
        float z = bs2f(zv[j]);
        float g = (bs2f(yv[j]) + bs2f(ucv[j]) * dv[j]) * (z / (1.f + __expf(-z)));
        o[j] = f2bs(g);
    }
    *(short8*)(uc + (size_t)row * DI + d8) = o;
}

extern "C" void kernel_launch(void* const* d_in, const int* in_sizes, int n_in,
                              void* d_out, int out_size, void* d_ws, size_t ws_size,
                              hipStream_t stream) {
    const float* x    = (const float*)d_in[0];
    const float* lnw  = (const float*)d_in[1];
    const float* lnb  = (const float*)d_in[2];
    const float* Win  = (const float*)d_in[3];
    const float* cw   = (const float*)d_in[4];
    const float* cb   = (const float*)d_in[5];
    const float* Wxp  = (const float*)d_in[6];
    const float* Wdt  = (const float*)d_in[7];
    const float* bdt  = (const float*)d_in[8];
    const float* Alog = (const float*)d_in[9];
    const float* Dp   = (const float*)d_in[10];
    const float* Wout = (const float*)d_in[11];
    float* out = (float*)d_out;           // reference output dtype = float32

    char* ws = (char*)d_ws;               // ~201.6 MB used
    bf16* xn    = (bf16*)(ws + 0);                 // 8192x1024
    bf16* WtIn  = (bf16*)(ws + 16777216);          // 4096x1024
    bf16* WtXp  = (bf16*)(ws + 25165824);          // 256x2048 (zero-padded)
    bf16* WtDt  = (bf16*)(ws + 26214400);          // 2048x64
    bf16* WtOut = (bf16*)(ws + 26476544);          // 1024x2048
    bf16* uz    = (bf16*)(ws + 30670848);          // 8192x4096 (u | z)
    bf16* uc    = (bf16*)(ws + 97779712);          // 8192x2048 (later g, in place)
    bf16* proj  = (bf16*)(ws + 131334144);         // 8192x192
    bf16* dtb   = (bf16*)(ws + 134479872);         // 8192x2048
    bf16* ysb   = (bf16*)(ws + 168034304);         // 8192x2048

    // weight transposes (Bt layouts, k-contiguous rows), f32 -> bf16
    transpose_pad<<<16384, 256, 0, stream>>>(Win,  WtIn,  1024, 10, 4096, 4096 * 1024);
    transpose_pad<<<2048,  256, 0, stream>>>(Wxp,  WtXp,  2048, 11, 192,  256 * 2048);
    transpose_pad<<<512,   256, 0, stream>>>(Wdt,  WtDt,  64,   6,  2048, 2048 * 64);
    transpose_pad<<<8192,  256, 0, stream>>>(Wout, WtOut, 2048, 11, 1024, 1024 * 2048);

    ln_kernel<<<2048, 256, 0, stream>>>(x, lnw, lnb, xn);
    gemm_bt<0><<<dim3(64, 32), 256, 0, stream>>>(xn, 1024, WtIn, 1024, 1024,
                                                 uz, nullptr, 4096, 4096, nullptr);
    conv_silu_kernel<<<8192, 256, 0, stream>>>(uz, cw, cb, uc);
    gemm_bt<0><<<dim3(64, 2), 256, 0, stream>>>(uc, 2048, WtXp, 2048, 2048,
                                                proj, nullptr, 192, 192, nullptr);
    gemm_bt<1><<<dim3(64, 16), 256, 0, stream>>>(proj, 192, WtDt, 64, 64,
                                                 dtb, nullptr, 2048, 2048, bdt);
    scan_kernel<<<2048, 256, 0, stream>>>(dtb, proj, uc, Alog, ysb);
    assemble_kernel<<<8192, 256, 0, stream>>>(ysb, uz, Dp, uc);
    gemm_bt<2><<<dim3(64, 8), 256, 0, stream>>>(uc, 2048, WtOut, 2048, 2048,
                                                nullptr, out, 1024, 1024, x);
}

// Round 9
// 826.171 us; speedup vs baseline: 2.1860x; 1.0104x over previous
//
#include <hip/hip_runtime.h>
#include <hip/hip_bf16.h>
#include <stdint.h>

#define SEQ   2048
#define DIM   1024
#define NST   64
#define DI    2048
#define DTR   64
#define ROWS  8192   // BATCH*SEQ

typedef __hip_bfloat16 bf16;
typedef __attribute__((ext_vector_type(8))) short short8;   // 8 bf16 = 4 VGPRs
typedef __attribute__((ext_vector_type(4))) short bs4x;     // 4 bf16 = 2 VGPRs
typedef __attribute__((ext_vector_type(4))) float f32x4;

typedef const __attribute__((address_space(1))) void gv_t;  // global
typedef __attribute__((address_space(3))) void lv_t;        // LDS

__device__ __forceinline__ float bs2f(short s) {
    return __uint_as_float(((uint32_t)(uint16_t)s) << 16);
}
__device__ __forceinline__ float lo16f(uint32_t u) {
    return __uint_as_float(u << 16);
}
__device__ __forceinline__ float hi16f(uint32_t u) {
    return __uint_as_float(u & 0xffff0000u);
}
__device__ __forceinline__ short f2bs(float f) {
    bf16 h = __float2bfloat16(f);
    return *(short*)&h;
}
__device__ __forceinline__ float b2f(bf16 v) { return __bfloat162float(v); }

// ------- transpose f32 -> bf16 with optional zero-pad: out[n][k] = in[k][n] --
__global__ __launch_bounds__(256) void transpose_pad(
    const float* __restrict__ in, bf16* __restrict__ out,
    int Kdim, int lgK, int Nin, int total)
{
    int idx = blockIdx.x * 256 + threadIdx.x;
    if (idx >= total) return;
    int n = idx >> lgK;
    int k = idx & (Kdim - 1);
    float v = (n < Nin) ? in[(size_t)k * Nin + n] : 0.f;
    out[idx] = __float2bfloat16(v);
}

// ---------------- LayerNorm: one wave per 1024-wide f32 row -> bf16 ---------
__global__ __launch_bounds__(256) void ln_kernel(
    const float* __restrict__ x, const float* __restrict__ w,
    const float* __restrict__ b, bf16* __restrict__ xn)
{
    int row  = blockIdx.x * 4 + (threadIdx.x >> 6);
    int lane = threadIdx.x & 63;
    const float4* xr = (const float4*)(x + (size_t)row * DIM);
    float4 v[4];
    float s = 0.f, s2 = 0.f;
#pragma unroll
    for (int q = 0; q < 4; ++q) {
        v[q] = xr[q * 64 + lane];
        s  += v[q].x + v[q].y + v[q].z + v[q].w;
        s2 += v[q].x*v[q].x + v[q].y*v[q].y + v[q].z*v[q].z + v[q].w*v[q].w;
    }
#pragma unroll
    for (int off = 32; off; off >>= 1) {
        s  += __shfl_xor(s, off);
        s2 += __shfl_xor(s2, off);
    }
    float mu  = s * (1.f / DIM);
    float var = s2 * (1.f / DIM) - mu * mu;
    float rs  = rsqrtf(var + 1e-5f);
    const float4* wp = (const float4*)w;
    const float4* bp = (const float4*)b;
#pragma unroll
    for (int q = 0; q < 4; ++q) {
        float4 wv = wp[q * 64 + lane];
        float4 bv = bp[q * 64 + lane];
        bs4x o;
        o[0] = f2bs((v[q].x - mu) * rs * wv.x + bv.x);
        o[1] = f2bs((v[q].y - mu) * rs * wv.y + bv.y);
        o[2] = f2bs((v[q].z - mu) * rs * wv.z + bv.z);
        o[3] = f2bs((v[q].w - mu) * rs * wv.w + bv.w);
        *(bs4x*)(xn + (size_t)row * DIM + (q * 64 + lane) * 4) = o;
    }
}

// ---------------- 128x128 BK=32 MFMA bf16 GEMM, Bt = [N][K] ----------------
// MODE 0: store bf16 (predicated col<nvalid). MODE 1: softplus(acc+bias[n]) bf16.
// MODE 2: acc + residual[m][n] (f32), store FLOAT (final output).
template<int MODE>
__global__ __launch_bounds__(256) void gemm_bt(
    const bf16* __restrict__ A, int lda,
    const bf16* __restrict__ Bt, int ldb, int K,
    bf16* __restrict__ outp, float* __restrict__ outF, int ldo, int nvalid,
    const float* __restrict__ aux)
{
    __shared__ alignas(16) bf16 As[128 * 32];
    __shared__ alignas(16) bf16 Bs[128 * 32];
    const int tid = threadIdx.x;
    const int wid = tid >> 6, lane = tid & 63;
    const int m0 = blockIdx.x * 128, n0 = blockIdx.y * 128;
    const int wr = wid >> 1, wc = wid & 1;

    f32x4 acc[4][4];
#pragma unroll
    for (int i = 0; i < 4; ++i)
#pragma unroll
        for (int j = 0; j < 4; ++j) acc[i][j] = (f32x4){0.f, 0.f, 0.f, 0.f};

    const int srow = tid >> 2;           // 0..63
    const int scol = (tid & 3) * 8;      // 0,8,16,24
    const bf16* ga = A  + (size_t)(m0 + srow) * lda + scol;
    const bf16* gb = Bt + (size_t)(n0 + srow) * ldb + scol;
    char* lA0 = (char*)As + wid * 1024;
    char* lA1 = (char*)As + 4096 + wid * 1024;
    char* lB0 = (char*)Bs + wid * 1024;
    char* lB1 = (char*)Bs + 4096 + wid * 1024;

    const int frow = lane & 15;
    const int fk   = (lane >> 4) * 8;

    for (int k0 = 0; k0 < K; k0 += 32) {
        __builtin_amdgcn_global_load_lds((gv_t*)(ga + k0),                      (lv_t*)lA0, 16, 0, 0);
        __builtin_amdgcn_global_load_lds((gv_t*)(ga + (size_t)64 * lda + k0),   (lv_t*)lA1, 16, 0, 0);
        __builtin_amdgcn_global_load_lds((gv_t*)(gb + k0),                      (lv_t*)lB0, 16, 0, 0);
        __builtin_amdgcn_global_load_lds((gv_t*)(gb + (size_t)64 * ldb + k0),   (lv_t*)lB1, 16, 0, 0);
        __syncthreads();
        short8 af[4], bf_[4];
#pragma unroll
        for (int i = 0; i < 4; ++i) {
            af[i]  = *(const short8*)((const char*)As + ((wr*64 + i*16 + frow) * 32 + fk) * 2);
            bf_[i] = *(const short8*)((const char*)Bs + ((wc*64 + i*16 + frow) * 32 + fk) * 2);
        }
#pragma unroll
        for (int i = 0; i < 4; ++i)
#pragma unroll
            for (int j = 0; j < 4; ++j)
                acc[i][j] = __builtin_amdgcn_mfma_f32_16x16x32_bf16(af[i], bf_[j], acc[i][j], 0, 0, 0);
        __syncthreads();
    }

    const int erow = wr * 64 + (lane >> 4) * 4;
    const int ecol = wc * 64 + (lane & 15);
#pragma unroll
    for (int i = 0; i < 4; ++i)
#pragma unroll
        for (int j = 0; j < 4; ++j)
#pragma unroll
            for (int r = 0; r < 4; ++r) {
                int gr = m0 + erow + i * 16 + r;
                int gc = n0 + ecol + j * 16;
                float v = acc[i][j][r];
                if (MODE == 0) {
                    if (gc < nvalid) outp[(size_t)gr * ldo + gc] = __float2bfloat16(v);
                } else if (MODE == 1) {
                    v += aux[gc];
                    float sp = fmaxf(v, 0.f) + log1pf(__expf(-fabsf(v)));
                    outp[(size_t)gr * ldo + gc] = __float2bfloat16(sp);
                } else {
                    v += aux[(size_t)gr * ldo + gc];
                    outF[(size_t)gr * ldo + gc] = v;      // f32 final output
                }
            }
}

// ---------------- depthwise causal conv (DCONV=4) + SiLU -------------------
__global__ __launch_bounds__(256) void conv_silu_kernel(
    const bf16* __restrict__ uz, const float* __restrict__ cw,
    const float* __restrict__ cb, bf16* __restrict__ uc)
{
    int row = blockIdx.x;                 // 0..8191  (b*SEQ + t)
    int d8  = threadIdx.x * 8;            // channel group base
    int t   = row & (SEQ - 1);
    float accv[8];
    float4 cb0 = *(const float4*)(cb + d8);
    float4 cb1 = *(const float4*)(cb + d8 + 4);
    accv[0]=cb0.x; accv[1]=cb0.y; accv[2]=cb0.z; accv[3]=cb0.w;
    accv[4]=cb1.x; accv[5]=cb1.y; accv[6]=cb1.z; accv[7]=cb1.w;
    const float4* cw4 = (const float4*)cw;   // one float4 per channel (4 taps)
    float4 wj[8];
#pragma unroll
    for (int j = 0; j < 8; ++j) wj[j] = cw4[d8 + j];
#pragma unroll
    for (int k = 0; k < 4; ++k) {
        int tt = t + k - 3;
        if (tt < 0) continue;             // block-uniform predicate
        short8 uv = *(const short8*)(uz + (size_t)(row + k - 3) * 4096 + d8);
        float wk[8] = {((const float*)&wj[0])[k], ((const float*)&wj[1])[k],
                       ((const float*)&wj[2])[k], ((const float*)&wj[3])[k],
                       ((const float*)&wj[4])[k], ((const float*)&wj[5])[k],
                       ((const float*)&wj[6])[k], ((const float*)&wj[7])[k]};
#pragma unroll
        for (int j = 0; j < 8; ++j)
            accv[j] += bs2f(uv[j]) * wk[j];
    }
    short8 o;
#pragma unroll
    for (int j = 0; j < 8; ++j) {
        float v = accv[j];
        o[j] = f2bs(v / (1.f + __expf(-v)));
    }
    *(short8*)(uc + (size_t)row * DI + d8) = o;
}

// ---------------- selective scan v3: wave per (b,d), lane = n, TILE=32 ------
// Staged per tile: BC packed (B|C<<16) [t][n] pad-65 (conflict-free);
// DTU4 = (dt, dt*u, u*D, z) per (wid,t). Inner: 7 VALU + exp2 + 3 DS.
// Epilogue fuses gate: uc <- (ysum + u*D) * silu(z)  (in place; assemble gone)
__global__ __launch_bounds__(256) void scan_kernel(
    const bf16* __restrict__ dt, const bf16* __restrict__ proj,
    bf16* __restrict__ uc, const bf16* __restrict__ uz,
    const float* __restrict__ A_log, const float* __restrict__ Dp)
{
    const int tid  = threadIdx.x;
    const int wid  = tid >> 6, lane = tid & 63;
    const int b    = blockIdx.x >> 9;
    const int dg   = blockIdx.x & 511;
    const int d    = dg * 4 + wid;
    const int rowbase = b * SEQ;

    __shared__ uint32_t BC[32][65];               // (B | C<<16), stride 65 dwords
    __shared__ float4 DTU4[4][32];                // (dt, dt*u, u*D, z)
    __shared__ alignas(16) short Pl[4][32 * 68];  // per-wave P[t][n], stride 68

    const float Aval2 = -__expf(A_log[d * NST + lane]) * 1.44269504f; // A*log2e
    float h = 0.f;

    // BC staging: 256 threads, 8 packs each
    const int sr = tid >> 3;                 // 0..31 (t)
    const int sc = (tid & 7) * 8;            // 0..56 (n group)
    // DTU staging: threads 0..127
    const int st = tid >> 2;                 // t (valid when tid<128)
    const int sw = tid & 3;                  // wid
    const int sd = dg * 4 + sw;
    const float Dd = Dp[sd];

    short* const prow_w = &Pl[wid][lane];             // + tt*68
    const short* const prow_r = &Pl[wid][lane * 68];  // lane = t (lane<32)

    for (int t0 = 0; t0 < SEQ; t0 += 32) {
        __syncthreads();   // previous tile fully consumed
        {
            const bf16* src = proj + (size_t)(rowbase + t0 + sr) * 192 + DTR + sc;
            short8 Bv8 = *(const short8*)src;
            short8 Cv8 = *(const short8*)(src + NST);
#pragma unroll
            for (int j = 0; j < 8; ++j)
                BC[sr][sc + j] = (uint16_t)Bv8[j] | ((uint32_t)(uint16_t)Cv8[j] << 16);
            if (tid < 128) {
                size_t ro = (size_t)(rowbase + t0 + st) * DI + sd;
                float dtv = b2f(dt[ro]);
                float uv  = b2f(uc[ro]);
                float zv  = b2f(uz[(size_t)(rowbase + t0 + st) * 4096 + DI + sd]);
                DTU4[sw][st] = make_float4(dtv, dtv * uv, uv * Dd, zv);
            }
        }
        __syncthreads();

#pragma unroll
        for (int tt = 0; tt < 32; ++tt) {
            uint32_t bc = BC[tt][lane];
            float2 du = *(const float2*)&DTU4[wid][tt];   // broadcast b64
            float Bv = lo16f(bc);
            float Cv = hi16f(bc);
            float dA = exp2f(du.x * Aval2);
            h = fmaf(h, dA, du.y * Bv);
            prow_w[tt * 68] = f2bs(h * Cv);
        }

        if (lane < 32) {   // lane = t: reduce over n + fused gate
            float ysum = 0.f;
#pragma unroll
            for (int j = 0; j < 8; ++j) {
                uint2 v = *(const uint2*)(prow_r + j * 4);
                ysum += lo16f(v.x) + hi16f(v.x) + lo16f(v.y) + hi16f(v.y);
            }
            float4 q = DTU4[wid][lane];
            float g = (ysum + q.z) * (q.w / (1.f + __expf(-q.w)));
            uc[(size_t)(rowbase + t0 + lane) * DI + d] = __float2bfloat16(g);
        }
    }
}

extern "C" void kernel_launch(void* const* d_in, const int* in_sizes, int n_in,
                              void* d_out, int out_size, void* d_ws, size_t ws_size,
                              hipStream_t stream) {
    const float* x    = (const float*)d_in[0];
    const float* lnw  = (const float*)d_in[1];
    const float* lnb  = (const float*)d_in[2];
    const float* Win  = (const float*)d_in[3];
    const float* cw   = (const float*)d_in[4];
    const float* cb   = (const float*)d_in[5];
    const float* Wxp  = (const float*)d_in[6];
    const float* Wdt  = (const float*)d_in[7];
    const float* bdt  = (const float*)d_in[8];
    const float* Alog = (const float*)d_in[9];
    const float* Dp   = (const float*)d_in[10];
    const float* Wout = (const float*)d_in[11];
    float* out = (float*)d_out;           // reference output dtype = float32

    char* ws = (char*)d_ws;
    bf16* xn    = (bf16*)(ws + 0);                 // 8192x1024
    bf16* WtIn  = (bf16*)(ws + 16777216);          // 4096x1024
    bf16* WtXp  = (bf16*)(ws + 25165824);          // 256x2048 (zero-padded)
    bf16* WtDt  = (bf16*)(ws + 26214400);          // 2048x64
    bf16* WtOut = (bf16*)(ws + 26476544);          // 1024x2048
    bf16* uz    = (bf16*)(ws + 30670848);          // 8192x4096 (u | z)
    bf16* uc    = (bf16*)(ws + 97779712);          // 8192x2048 (u_c, then g in place)
    bf16* proj  = (bf16*)(ws + 131334144);         // 8192x192
    bf16* dtb   = (bf16*)(ws + 134479872);         // 8192x2048

    // weight transposes (Bt layouts, k-contiguous rows), f32 -> bf16
    transpose_pad<<<16384, 256, 0, stream>>>(Win,  WtIn,  1024, 10, 4096, 4096 * 1024);
    transpose_pad<<<2048,  256, 0, stream>>>(Wxp,  WtXp,  2048, 11, 192,  256 * 2048);
    transpose_pad<<<512,   256, 0, stream>>>(Wdt,  WtDt,  64,   6,  2048, 2048 * 64);
    transpose_pad<<<8192,  256, 0, stream>>>(Wout, WtOut, 2048, 11, 1024, 1024 * 2048);

    ln_kernel<<<2048, 256, 0, stream>>>(x, lnw, lnb, xn);
    gemm_bt<0><<<dim3(64, 32), 256, 0, stream>>>(xn, 1024, WtIn, 1024, 1024,
                                                 uz, nullptr, 4096, 4096, nullptr);
    conv_silu_kernel<<<8192, 256, 0, stream>>>(uz, cw, cb, uc);
    gemm_bt<0><<<dim3(64, 2), 256, 0, stream>>>(uc, 2048, WtXp, 2048, 2048,
                                                proj, nullptr, 192, 192, nullptr);
    gemm_bt<1><<<dim3(64, 16), 256, 0, stream>>>(proj, 192, WtDt, 64, 64,
                                                 dtb, nullptr, 2048, 2048, bdt);
    scan_kernel<<<2048, 256, 0, stream>>>(dtb, proj, uc, uz, Alog, Dp);
    gemm_bt<2><<<dim3(64, 8), 256, 0, stream>>>(uc, 2048, WtOut, 2048, 2048,
                                                nullptr, out, 1024, 1024, x);
}

// Round 10
// 802.956 us; speedup vs baseline: 2.2492x; 1.0289x over previous
//
#include <hip/hip_runtime.h>
#include <hip/hip_bf16.h>
#include <stdint.h>

#define SEQ   2048
#define DIM   1024
#define NST   64
#define DI    2048
#define DTR   64
#define ROWS  8192   // BATCH*SEQ

typedef __hip_bfloat16 bf16;
typedef __attribute__((ext_vector_type(8))) short short8;   // 8 bf16 = 4 VGPRs
typedef __attribute__((ext_vector_type(4))) short bs4x;     // 4 bf16 = 2 VGPRs
typedef __attribute__((ext_vector_type(4))) float f32x4;

typedef const __attribute__((address_space(1))) void gv_t;  // global
typedef __attribute__((address_space(3))) void lv_t;        // LDS

__device__ __forceinline__ float bs2f(short s) {
    return __uint_as_float(((uint32_t)(uint16_t)s) << 16);
}
__device__ __forceinline__ short f2bs(float f) {
    bf16 h = __float2bfloat16(f);
    return *(short*)&h;
}
__device__ __forceinline__ float b2f(bf16 v) { return __bfloat162float(v); }

// ------- transpose f32 -> bf16 with optional zero-pad: out[n][k] = in[k][n] --
__global__ __launch_bounds__(256) void transpose_pad(
    const float* __restrict__ in, bf16* __restrict__ out,
    int Kdim, int lgK, int Nin, int total)
{
    int idx = blockIdx.x * 256 + threadIdx.x;
    if (idx >= total) return;
    int n = idx >> lgK;
    int k = idx & (Kdim - 1);
    float v = (n < Nin) ? in[(size_t)k * Nin + n] : 0.f;
    out[idx] = __float2bfloat16(v);
}

// ---------------- LayerNorm: one wave per 1024-wide f32 row -> bf16 ---------
__global__ __launch_bounds__(256) void ln_kernel(
    const float* __restrict__ x, const float* __restrict__ w,
    const float* __restrict__ b, bf16* __restrict__ xn)
{
    int row  = blockIdx.x * 4 + (threadIdx.x >> 6);
    int lane = threadIdx.x & 63;
    const float4* xr = (const float4*)(x + (size_t)row * DIM);
    float4 v[4];
    float s = 0.f, s2 = 0.f;
#pragma unroll
    for (int q = 0; q < 4; ++q) {
        v[q] = xr[q * 64 + lane];
        s  += v[q].x + v[q].y + v[q].z + v[q].w;
        s2 += v[q].x*v[q].x + v[q].y*v[q].y + v[q].z*v[q].z + v[q].w*v[q].w;
    }
#pragma unroll
    for (int off = 32; off; off >>= 1) {
        s  += __shfl_xor(s, off);
        s2 += __shfl_xor(s2, off);
    }
    float mu  = s * (1.f / DIM);
    float var = s2 * (1.f / DIM) - mu * mu;
    float rs  = rsqrtf(var + 1e-5f);
    const float4* wp = (const float4*)w;
    const float4* bp = (const float4*)b;
#pragma unroll
    for (int q = 0; q < 4; ++q) {
        float4 wv = wp[q * 64 + lane];
        float4 bv = bp[q * 64 + lane];
        bs4x o;
        o[0] = f2bs((v[q].x - mu) * rs * wv.x + bv.x);
        o[1] = f2bs((v[q].y - mu) * rs * wv.y + bv.y);
        o[2] = f2bs((v[q].z - mu) * rs * wv.z + bv.z);
        o[3] = f2bs((v[q].w - mu) * rs * wv.w + bv.w);
        *(bs4x*)(xn + (size_t)row * DIM + (q * 64 + lane) * 4) = o;
    }
}

// ---------------- 128x128 BK=32 MFMA bf16 GEMM, Bt = [N][K] ----------------
// MODE 0: store bf16 (predicated col<nvalid). MODE 1: softplus(acc+bias[n]) bf16.
// MODE 2: acc + residual[m][n] (f32), store FLOAT (final output).
template<int MODE>
__global__ __launch_bounds__(256) void gemm_bt(
    const bf16* __restrict__ A, int lda,
    const bf16* __restrict__ Bt, int ldb, int K,
    bf16* __restrict__ outp, float* __restrict__ outF, int ldo, int nvalid,
    const float* __restrict__ aux)
{
    __shared__ alignas(16) bf16 As[128 * 32];
    __shared__ alignas(16) bf16 Bs[128 * 32];
    const int tid = threadIdx.x;
    const int wid = tid >> 6, lane = tid & 63;
    const int m0 = blockIdx.x * 128, n0 = blockIdx.y * 128;
    const int wr = wid >> 1, wc = wid & 1;

    f32x4 acc[4][4];
#pragma unroll
    for (int i = 0; i < 4; ++i)
#pragma unroll
        for (int j = 0; j < 4; ++j) acc[i][j] = (f32x4){0.f, 0.f, 0.f, 0.f};

    const int srow = tid >> 2;           // 0..63
    const int scol = (tid & 3) * 8;      // 0,8,16,24
    const bf16* ga = A  + (size_t)(m0 + srow) * lda + scol;
    const bf16* gb = Bt + (size_t)(n0 + srow) * ldb + scol;
    char* lA0 = (char*)As + wid * 1024;
    char* lA1 = (char*)As + 4096 + wid * 1024;
    char* lB0 = (char*)Bs + wid * 1024;
    char* lB1 = (char*)Bs + 4096 + wid * 1024;

    const int frow = lane & 15;
    const int fk   = (lane >> 4) * 8;

    for (int k0 = 0; k0 < K; k0 += 32) {
        __builtin_amdgcn_global_load_lds((gv_t*)(ga + k0),                      (lv_t*)lA0, 16, 0, 0);
        __builtin_amdgcn_global_load_lds((gv_t*)(ga + (size_t)64 * lda + k0),   (lv_t*)lA1, 16, 0, 0);
        __builtin_amdgcn_global_load_lds((gv_t*)(gb + k0),                      (lv_t*)lB0, 16, 0, 0);
        __builtin_amdgcn_global_load_lds((gv_t*)(gb + (size_t)64 * ldb + k0),   (lv_t*)lB1, 16, 0, 0);
        __syncthreads();
        short8 af[4], bf_[4];
#pragma unroll
        for (int i = 0; i < 4; ++i) {
            af[i]  = *(const short8*)((const char*)As + ((wr*64 + i*16 + frow) * 32 + fk) * 2);
            bf_[i] = *(const short8*)((const char*)Bs + ((wc*64 + i*16 + frow) * 32 + fk) * 2);
        }
#pragma unroll
        for (int i = 0; i < 4; ++i)
#pragma unroll
            for (int j = 0; j < 4; ++j)
                acc[i][j] = __builtin_amdgcn_mfma_f32_16x16x32_bf16(af[i], bf_[j], acc[i][j], 0, 0, 0);
        __syncthreads();
    }

    const int erow = wr * 64 + (lane >> 4) * 4;
    const int ecol = wc * 64 + (lane & 15);
#pragma unroll
    for (int i = 0; i < 4; ++i)
#pragma unroll
        for (int j = 0; j < 4; ++j)
#pragma unroll
            for (int r = 0; r < 4; ++r) {
                int gr = m0 + erow + i * 16 + r;
                int gc = n0 + ecol + j * 16;
                float v = acc[i][j][r];
                if (MODE == 0) {
                    if (gc < nvalid) outp[(size_t)gr * ldo + gc] = __float2bfloat16(v);
                } else if (MODE == 1) {
                    v += aux[gc];
                    float sp = fmaxf(v, 0.f) + log1pf(__expf(-fabsf(v)));
                    outp[(size_t)gr * ldo + gc] = __float2bfloat16(sp);
                } else {
                    v += aux[(size_t)gr * ldo + gc];
                    outF[(size_t)gr * ldo + gc] = v;      // f32 final output
                }
            }
}

// ---------------- depthwise causal conv (DCONV=4) + SiLU -------------------
__global__ __launch_bounds__(256) void conv_silu_kernel(
    const bf16* __restrict__ uz, const float* __restrict__ cw,
    const float* __restrict__ cb, bf16* __restrict__ uc)
{
    int row = blockIdx.x;                 // 0..8191  (b*SEQ + t)
    int d8  = threadIdx.x * 8;            // channel group base
    int t   = row & (SEQ - 1);
    float accv[8];
    float4 cb0 = *(const float4*)(cb + d8);
    float4 cb1 = *(const float4*)(cb + d8 + 4);
    accv[0]=cb0.x; accv[1]=cb0.y; accv[2]=cb0.z; accv[3]=cb0.w;
    accv[4]=cb1.x; accv[5]=cb1.y; accv[6]=cb1.z; accv[7]=cb1.w;
    const float4* cw4 = (const float4*)cw;   // one float4 per channel (4 taps)
    float4 wj[8];
#pragma unroll
    for (int j = 0; j < 8; ++j) wj[j] = cw4[d8 + j];
#pragma unroll
    for (int k = 0; k < 4; ++k) {
        int tt = t + k - 3;
        if (tt < 0) continue;             // block-uniform predicate
        short8 uv = *(const short8*)(uz + (size_t)(row + k - 3) * 4096 + d8);
        float wk[8] = {((const float*)&wj[0])[k], ((const float*)&wj[1])[k],
                       ((const float*)&wj[2])[k], ((const float*)&wj[3])[k],
                       ((const float*)&wj[4])[k], ((const float*)&wj[5])[k],
                       ((const float*)&wj[6])[k], ((const float*)&wj[7])[k]};
#pragma unroll
        for (int j = 0; j < 8; ++j)
            accv[j] += bs2f(uv[j]) * wk[j];
    }
    short8 o;
#pragma unroll
    for (int j = 0; j < 8; ++j) {
        float v = accv[j];
        o[j] = f2bs(v / (1.f + __expf(-v)));
    }
    *(short8*)(uc + (size_t)row * DI + d8) = o;
}

// ---------------- selective scan v4: wave per (b,d), lane = n, TILE=32 ------
// B/C tiles staged via global_load_lds (zero VALU). Inner loop:
// 2x ds_read_u16 + 1x b64 broadcast + 1x ds_write_b32(f32 P) +
// {2 shl, 1 mul, 1 raw v_exp, 1 fma, 1 mul}. P stride 67 (odd) = conflict-free.
// Reduce: all 64 lanes (half row each) + shfl_xor(32); fused gate writes uc.
__global__ __launch_bounds__(256) void scan_kernel(
    const bf16* __restrict__ dt, const bf16* __restrict__ proj,
    bf16* __restrict__ uc, const bf16* __restrict__ uz,
    const float* __restrict__ A_log, const float* __restrict__ Dp)
{
    const int tid  = threadIdx.x;
    const int wid  = tid >> 6, lane = tid & 63;
    const int b    = blockIdx.x >> 9;
    const int dg   = blockIdx.x & 511;
    const int d    = dg * 4 + wid;
    const int rowbase = b * SEQ;

    __shared__ alignas(16) bf16 Bsh[32][64];      // 4 KB
    __shared__ alignas(16) bf16 Csh[32][64];      // 4 KB
    __shared__ float2 DTU[4][32];                 // (dt, dt*u)  1 KB
    __shared__ float2 GZ[4][32];                  // (u*D, z)    1 KB
    __shared__ float Pf[4][32 * 67];              // 34.3 KB, odd stride

    const float Aval2 = -__expf(A_log[d * NST + lane]) * 1.44269504f; // A*log2e
    float h = 0.f;

    // DTU staging: threads 0..127
    const int st = tid >> 2;                 // t
    const int sw = tid & 3;                  // wid
    const int sd = dg * 4 + sw;
    const float Dd = Dp[sd];

    // B/C gload: wave wid stages rows [wid*8, wid*8+8)
    const bf16* bsrc = proj + (size_t)(rowbase + wid * 8 + (lane >> 3)) * 192
                            + DTR + (lane & 7) * 8;
    lv_t* bdst = (lv_t*)((char*)Bsh + wid * 1024);
    lv_t* cdst = (lv_t*)((char*)Csh + wid * 1024);

    float* const pw = &Pf[wid][lane];               // + tt*67
    const float* const pr = &Pf[wid][(lane & 31) * 67 + (lane >> 5) * 32];

    for (int t0 = 0; t0 < SEQ; t0 += 32) {
        __syncthreads();   // previous tile fully consumed
        __builtin_amdgcn_global_load_lds((gv_t*)(bsrc + (size_t)t0 * 192),       bdst, 16, 0, 0);
        __builtin_amdgcn_global_load_lds((gv_t*)(bsrc + (size_t)t0 * 192 + NST), cdst, 16, 0, 0);
        if (tid < 128) {
            size_t ro = (size_t)(rowbase + t0 + st) * DI + sd;
            float dtv = b2f(dt[ro]);
            float uv  = b2f(uc[ro]);
            float zv  = b2f(uz[(size_t)(rowbase + t0 + st) * 4096 + DI + sd]);
            DTU[sw][st] = make_float2(dtv, dtv * uv);
            GZ [sw][st] = make_float2(uv * Dd, zv);
        }
        __syncthreads();   // drains vmcnt (gload) + lgkm

#pragma unroll
        for (int tt = 0; tt < 32; ++tt) {
            float Bv = b2f(Bsh[tt][lane]);           // ds_read_u16 + shl
            float Cv = b2f(Csh[tt][lane]);
            float2 du = DTU[wid][tt];                // b64 broadcast
            float dA = __builtin_amdgcn_exp2f(du.x * Aval2);
            h = fmaf(h, dA, du.y * Bv);
            pw[tt * 67] = h * Cv;                    // ds_write_b32, 2-way free
        }

        // reduce: lane = (t | half<<5); conflict-free odd-stride reads
        float ysum = 0.f;
#pragma unroll
        for (int j = 0; j < 32; ++j) ysum += pr[j];
        ysum += __shfl_xor(ysum, 32);
        if (lane < 32) {
            float2 q = GZ[wid][lane];
            float g = (ysum + q.x) * (q.y / (1.f + __expf(-q.y)));
            uc[(size_t)(rowbase + t0 + lane) * DI + d] = __float2bfloat16(g);
        }
    }
}

extern "C" void kernel_launch(void* const* d_in, const int* in_sizes, int n_in,
                              void* d_out, int out_size, void* d_ws, size_t ws_size,
                              hipStream_t stream) {
    const float* x    = (const float*)d_in[0];
    const float* lnw  = (const float*)d_in[1];
    const float* lnb  = (const float*)d_in[2];
    const float* Win  = (const float*)d_in[3];
    const float* cw   = (const float*)d_in[4];
    const float* cb   = (const float*)d_in[5];
    const float* Wxp  = (const float*)d_in[6];
    const float* Wdt  = (const float*)d_in[7];
    const float* bdt  = (const float*)d_in[8];
    const float* Alog = (const float*)d_in[9];
    const float* Dp   = (const float*)d_in[10];
    const float* Wout = (const float*)d_in[11];
    float* out = (float*)d_out;           // reference output dtype = float32

    char* ws = (char*)d_ws;
    bf16* xn    = (bf16*)(ws + 0);                 // 8192x1024
    bf16* WtIn  = (bf16*)(ws + 16777216);          // 4096x1024
    bf16* WtXp  = (bf16*)(ws + 25165824);          // 256x2048 (zero-padded)
    bf16* WtDt  = (bf16*)(ws + 26214400);          // 2048x64
    bf16* WtOut = (bf16*)(ws + 26476544);          // 1024x2048
    bf16* uz    = (bf16*)(ws + 30670848);          // 8192x4096 (u | z)
    bf16* uc    = (bf16*)(ws + 97779712);          // 8192x2048 (u_c, then g in place)
    bf16* proj  = (bf16*)(ws + 131334144);         // 8192x192
    bf16* dtb   = (bf16*)(ws + 134479872);         // 8192x2048

    // weight transposes (Bt layouts, k-contiguous rows), f32 -> bf16
    transpose_pad<<<16384, 256, 0, stream>>>(Win,  WtIn,  1024, 10, 4096, 4096 * 1024);
    transpose_pad<<<2048,  256, 0, stream>>>(Wxp,  WtXp,  2048, 11, 192,  256 * 2048);
    transpose_pad<<<512,   256, 0, stream>>>(Wdt,  WtDt,  64,   6,  2048, 2048 * 64);
    transpose_pad<<<8192,  256, 0, stream>>>(Wout, WtOut, 2048, 11, 1024, 1024 * 2048);

    ln_kernel<<<2048, 256, 0, stream>>>(x, lnw, lnb, xn);
    gemm_bt<0><<<dim3(64, 32), 256, 0, stream>>>(xn, 1024, WtIn, 1024, 1024,
                                                 uz, nullptr, 4096, 4096, nullptr);
    conv_silu_kernel<<<8192, 256, 0, stream>>>(uz, cw, cb, uc);
    gemm_bt<0><<<dim3(64, 2), 256, 0, stream>>>(uc, 2048, WtXp, 2048, 2048,
                                                proj, nullptr, 192, 192, nullptr);
    gemm_bt<1><<<dim3(64, 16), 256, 0, stream>>>(proj, 192, WtDt, 64, 64,
                                                 dtb, nullptr, 2048, 2048, bdt);
    scan_kernel<<<2048, 256, 0, stream>>>(dtb, proj, uc, uz, Alog, Dp);
    gemm_bt<2><<<dim3(64, 8), 256, 0, stream>>>(uc, 2048, WtOut, 2048, 2048,
                                                nullptr, out, 1024, 1024, x);
}

// Round 11
// 749.431 us; speedup vs baseline: 2.4099x; 1.0714x over previous
//
#include <hip/hip_runtime.h>
#include <hip/hip_bf16.h>
#include <stdint.h>

#define SEQ   2048
#define DIM   1024
#define NST   64
#define DI    2048
#define DTR   64
#define ROWS  8192   // BATCH*SEQ

typedef __hip_bfloat16 bf16;
typedef __attribute__((ext_vector_type(8))) short short8;   // 8 bf16 = 4 VGPRs
typedef __attribute__((ext_vector_type(4))) short bs4x;     // 4 bf16 = 2 VGPRs
typedef __attribute__((ext_vector_type(4))) float f32x4;

typedef const __attribute__((address_space(1))) void gv_t;  // global
typedef __attribute__((address_space(3))) void lv_t;        // LDS

__device__ __forceinline__ float bs2f(short s) {
    return __uint_as_float(((uint32_t)(uint16_t)s) << 16);
}
__device__ __forceinline__ float lo16f(uint32_t u) {
    return __uint_as_float(u << 16);
}
__device__ __forceinline__ float hi16f(uint32_t u) {
    return __uint_as_float(u & 0xffff0000u);
}
__device__ __forceinline__ short f2bs(float f) {
    bf16 h = __float2bfloat16(f);
    return *(short*)&h;
}
__device__ __forceinline__ float b2f(bf16 v) { return __bfloat162float(v); }

// ------- transpose f32 -> bf16 with optional zero-pad: out[n][k] = in[k][n] --
__global__ __launch_bounds__(256) void transpose_pad(
    const float* __restrict__ in, bf16* __restrict__ out,
    int Kdim, int lgK, int Nin, int total)
{
    int idx = blockIdx.x * 256 + threadIdx.x;
    if (idx >= total) return;
    int n = idx >> lgK;
    int k = idx & (Kdim - 1);
    float v = (n < Nin) ? in[(size_t)k * Nin + n] : 0.f;
    out[idx] = __float2bfloat16(v);
}

// ---------------- LayerNorm: one wave per 1024-wide f32 row -> bf16 ---------
__global__ __launch_bounds__(256) void ln_kernel(
    const float* __restrict__ x, const float* __restrict__ w,
    const float* __restrict__ b, bf16* __restrict__ xn)
{
    int row  = blockIdx.x * 4 + (threadIdx.x >> 6);
    int lane = threadIdx.x & 63;
    const float4* xr = (const float4*)(x + (size_t)row * DIM);
    float4 v[4];
    float s = 0.f, s2 = 0.f;
#pragma unroll
    for (int q = 0; q < 4; ++q) {
        v[q] = xr[q * 64 + lane];
        s  += v[q].x + v[q].y + v[q].z + v[q].w;
        s2 += v[q].x*v[q].x + v[q].y*v[q].y + v[q].z*v[q].z + v[q].w*v[q].w;
    }
#pragma unroll
    for (int off = 32; off; off >>= 1) {
        s  += __shfl_xor(s, off);
        s2 += __shfl_xor(s2, off);
    }
    float mu  = s * (1.f / DIM);
    float var = s2 * (1.f / DIM) - mu * mu;
    float rs  = rsqrtf(var + 1e-5f);
    const float4* wp = (const float4*)w;
    const float4* bp = (const float4*)b;
#pragma unroll
    for (int q = 0; q < 4; ++q) {
        float4 wv = wp[q * 64 + lane];
        float4 bv = bp[q * 64 + lane];
        bs4x o;
        o[0] = f2bs((v[q].x - mu) * rs * wv.x + bv.x);
        o[1] = f2bs((v[q].y - mu) * rs * wv.y + bv.y);
        o[2] = f2bs((v[q].z - mu) * rs * wv.z + bv.z);
        o[3] = f2bs((v[q].w - mu) * rs * wv.w + bv.w);
        *(bs4x*)(xn + (size_t)row * DIM + (q * 64 + lane) * 4) = o;
    }
}

// ---------------- 128x128 BK=32 MFMA bf16 GEMM, Bt = [N][K] ----------------
// MODE 0: store bf16 (predicated col<nvalid). MODE 1: softplus(acc+bias[n]) bf16.
// MODE 2: acc + residual[m][n] (f32), store FLOAT (final output).
template<int MODE>
__global__ __launch_bounds__(256) void gemm_bt(
    const bf16* __restrict__ A, int lda,
    const bf16* __restrict__ Bt, int ldb, int K,
    bf16* __restrict__ outp, float* __restrict__ outF, int ldo, int nvalid,
    const float* __restrict__ aux)
{
    __shared__ alignas(16) bf16 As[128 * 32];
    __shared__ alignas(16) bf16 Bs[128 * 32];
    const int tid = threadIdx.x;
    const int wid = tid >> 6, lane = tid & 63;
    const int m0 = blockIdx.x * 128, n0 = blockIdx.y * 128;
    const int wr = wid >> 1, wc = wid & 1;

    f32x4 acc[4][4];
#pragma unroll
    for (int i = 0; i < 4; ++i)
#pragma unroll
        for (int j = 0; j < 4; ++j) acc[i][j] = (f32x4){0.f, 0.f, 0.f, 0.f};

    const int srow = tid >> 2;           // 0..63
    const int scol = (tid & 3) * 8;      // 0,8,16,24
    const bf16* ga = A  + (size_t)(m0 + srow) * lda + scol;
    const bf16* gb = Bt + (size_t)(n0 + srow) * ldb + scol;
    char* lA0 = (char*)As + wid * 1024;
    char* lA1 = (char*)As + 4096 + wid * 1024;
    char* lB0 = (char*)Bs + wid * 1024;
    char* lB1 = (char*)Bs + 4096 + wid * 1024;

    const int frow = lane & 15;
    const int fk   = (lane >> 4) * 8;

    for (int k0 = 0; k0 < K; k0 += 32) {
        __builtin_amdgcn_global_load_lds((gv_t*)(ga + k0),                      (lv_t*)lA0, 16, 0, 0);
        __builtin_amdgcn_global_load_lds((gv_t*)(ga + (size_t)64 * lda + k0),   (lv_t*)lA1, 16, 0, 0);
        __builtin_amdgcn_global_load_lds((gv_t*)(gb + k0),                      (lv_t*)lB0, 16, 0, 0);
        __builtin_amdgcn_global_load_lds((gv_t*)(gb + (size_t)64 * ldb + k0),   (lv_t*)lB1, 16, 0, 0);
        __syncthreads();
        short8 af[4], bf_[4];
#pragma unroll
        for (int i = 0; i < 4; ++i) {
            af[i]  = *(const short8*)((const char*)As + ((wr*64 + i*16 + frow) * 32 + fk) * 2);
            bf_[i] = *(const short8*)((const char*)Bs + ((wc*64 + i*16 + frow) * 32 + fk) * 2);
        }
#pragma unroll
        for (int i = 0; i < 4; ++i)
#pragma unroll
            for (int j = 0; j < 4; ++j)
                acc[i][j] = __builtin_amdgcn_mfma_f32_16x16x32_bf16(af[i], bf_[j], acc[i][j], 0, 0, 0);
        __syncthreads();
    }

    const int erow = wr * 64 + (lane >> 4) * 4;
    const int ecol = wc * 64 + (lane & 15);
#pragma unroll
    for (int i = 0; i < 4; ++i)
#pragma unroll
        for (int j = 0; j < 4; ++j)
#pragma unroll
            for (int r = 0; r < 4; ++r) {
                int gr = m0 + erow + i * 16 + r;
                int gc = n0 + ecol + j * 16;
                float v = acc[i][j][r];
                if (MODE == 0) {
                    if (gc < nvalid) outp[(size_t)gr * ldo + gc] = __float2bfloat16(v);
                } else if (MODE == 1) {
                    v += aux[gc];
                    float sp = fmaxf(v, 0.f) + log1pf(__expf(-fabsf(v)));
                    outp[(size_t)gr * ldo + gc] = __float2bfloat16(sp);
                } else {
                    v += aux[(size_t)gr * ldo + gc];
                    outF[(size_t)gr * ldo + gc] = v;      // f32 final output
                }
            }
}

// ---------------- depthwise causal conv (DCONV=4) + SiLU -------------------
__global__ __launch_bounds__(256) void conv_silu_kernel(
    const bf16* __restrict__ uz, const float* __restrict__ cw,
    const float* __restrict__ cb, bf16* __restrict__ uc)
{
    int row = blockIdx.x;                 // 0..8191  (b*SEQ + t)
    int d8  = threadIdx.x * 8;            // channel group base
    int t   = row & (SEQ - 1);
    float accv[8];
    float4 cb0 = *(const float4*)(cb + d8);
    float4 cb1 = *(const float4*)(cb + d8 + 4);
    accv[0]=cb0.x; accv[1]=cb0.y; accv[2]=cb0.z; accv[3]=cb0.w;
    accv[4]=cb1.x; accv[5]=cb1.y; accv[6]=cb1.z; accv[7]=cb1.w;
    const float4* cw4 = (const float4*)cw;   // one float4 per channel (4 taps)
    float4 wj[8];
#pragma unroll
    for (int j = 0; j < 8; ++j) wj[j] = cw4[d8 + j];
#pragma unroll
    for (int k = 0; k < 4; ++k) {
        int tt = t + k - 3;
        if (tt < 0) continue;             // block-uniform predicate
        short8 uv = *(const short8*)(uz + (size_t)(row + k - 3) * 4096 + d8);
        float wk[8] = {((const float*)&wj[0])[k], ((const float*)&wj[1])[k],
                       ((const float*)&wj[2])[k], ((const float*)&wj[3])[k],
                       ((const float*)&wj[4])[k], ((const float*)&wj[5])[k],
                       ((const float*)&wj[6])[k], ((const float*)&wj[7])[k]};
#pragma unroll
        for (int j = 0; j < 8; ++j)
            accv[j] += bs2f(uv[j]) * wk[j];
    }
    short8 o;
#pragma unroll
    for (int j = 0; j < 8; ++j) {
        float v = accv[j];
        o[j] = f2bs(v / (1.f + __expf(-v)));
    }
    *(short8*)(uc + (size_t)row * DI + d8) = o;
}

// ---------------- selective scan v5: wave per (b,d), lane = n, TILE=32 ------
// Double-buffered reg-staged packed BC[t][n] u32 (1 ds_read_b32/step);
// dt/dtu per-step scalars via v_readlane (no DTU LDS); P packed bf16 pairs
// via v_perm; fused gate. One barrier per tile; loads issued a tile ahead.
__global__ __launch_bounds__(256) void scan_kernel(
    const bf16* __restrict__ dt, const bf16* __restrict__ proj,
    bf16* __restrict__ uc, const bf16* __restrict__ uz,
    const float* __restrict__ A_log, const float* __restrict__ Dp)
{
    const int tid  = threadIdx.x;
    const int wid  = tid >> 6, lane = tid & 63;
    const int b    = blockIdx.x >> 9;
    const int dg   = blockIdx.x & 511;
    const int d    = dg * 4 + wid;
    const int rowbase = b * SEQ;

    __shared__ uint32_t BCt[2][32][65];       // (B | C<<16) [buf][t][n], 16.6 KB
    __shared__ uint32_t Pp[4][16 * 66];       // bf16-pair P per wave, 16.9 KB

    const float Aval2 = -__expf(A_log[d * NST + lane]) * 1.44269504f;
    const float Dd = Dp[d];
    float h = 0.f;

    // BC staging map: thread -> (row sr, cols sc..sc+7)
    const int sr = tid >> 3;              // 0..31
    const int sc = (tid & 7) * 8;         // 0..56
    const bf16* bc_src = proj + (size_t)(rowbase + sr) * 192 + DTR + sc;

    uint32_t* const pw_base = &Pp[wid][0];

    // ---- prologue: tile 0 ----
    uint4 Br = *(const uint4*)(bc_src);
    uint4 Cr = *(const uint4*)(bc_src + NST);
    uint16_t dt_u = 0, uc_u = 0, z_u = 0;
    if (lane < 32) {
        size_t r0 = (size_t)(rowbase + lane) * DI + d;
        dt_u = *(const uint16_t*)&dt[r0];
        uc_u = *(const uint16_t*)&uc[r0];
        z_u  = *(const uint16_t*)&uz[(size_t)(rowbase + lane) * 4096 + DI + d];
    }
    {
        const uint16_t* bp = (const uint16_t*)&Br;
        const uint16_t* cp = (const uint16_t*)&Cr;
#pragma unroll
        for (int j = 0; j < 8; ++j)
            BCt[0][sr][sc + j] = (uint32_t)bp[j] | ((uint32_t)cp[j] << 16);
    }
    float dtv_c = bs2f((short)dt_u);
    float ucv   = bs2f((short)uc_u);
    float dtu_c = dtv_c * ucv;
    float ud_c  = ucv * Dd;
    float z_c   = bs2f((short)z_u);
    __syncthreads();

    int cur = 0;
    for (int t0 = 0; t0 < SEQ; t0 += 32) {
        const bool more = (t0 + 32) < SEQ;
        // (A) issue next-tile loads (raw, no conversion -> no early vmcnt wait)
        if (more) {
            Br = *(const uint4*)(bc_src + (size_t)(t0 + 32) * 192);
            Cr = *(const uint4*)(bc_src + (size_t)(t0 + 32) * 192 + NST);
            if (lane < 32) {
                size_t rn = (size_t)(rowbase + t0 + 32 + lane) * DI + d;
                dt_u = *(const uint16_t*)&dt[rn];
                uc_u = *(const uint16_t*)&uc[rn];
                z_u  = *(const uint16_t*)&uz[(size_t)(rowbase + t0 + 32 + lane) * 4096 + DI + d];
            }
        }
        // (B) 32 scan steps
        const uint32_t* bc_t = &BCt[cur][0][lane];
        float p_even = 0.f;
#pragma unroll
        for (int tt = 0; tt < 32; ++tt) {
            uint32_t bc = bc_t[tt * 65];
            float Bv = lo16f(bc);
            float Cv = hi16f(bc);
            float sdt = __uint_as_float(
                (uint32_t)__builtin_amdgcn_readlane((int)__float_as_uint(dtv_c), tt));
            float sdu = __uint_as_float(
                (uint32_t)__builtin_amdgcn_readlane((int)__float_as_uint(dtu_c), tt));
            float dA = __builtin_amdgcn_exp2f(sdt * Aval2);
            h = fmaf(h, dA, sdu * Bv);
            float pv = h * Cv;
            if (tt & 1)
                pw_base[(tt >> 1) * 66 + lane] = __builtin_amdgcn_perm(
                    __float_as_uint(pv), __float_as_uint(p_even), 0x07060302u);
            else
                p_even = pv;
        }
        __builtin_amdgcn_sched_barrier(0);   // keep P writes before reduce reads
        // (C) reduce: lane (p=lane>>2, g=lane&3) sums 16 cols of pair-row p
        float ylo = 0.f, yhi = 0.f;
        const uint32_t* prow = pw_base + (lane >> 2) * 66 + (lane & 3) * 16;
#pragma unroll
        for (int j = 0; j < 8; ++j) {
            uint2 v = *(const uint2*)(prow + 2 * j);
            ylo += lo16f(v.x) + lo16f(v.y);
            yhi += hi16f(v.x) + hi16f(v.y);
        }
        ylo += __shfl_xor(ylo, 1); yhi += __shfl_xor(yhi, 1);
        ylo += __shfl_xor(ylo, 2); yhi += __shfl_xor(yhi, 2);
        int srcl = (lane >> 1) << 2;
        float ylo_b = __shfl(ylo, srcl);
        float yhi_b = __shfl(yhi, srcl);
        float ysum = (lane & 1) ? yhi_b : ylo_b;
        if (lane < 32) {
            float g = (ysum + ud_c) * (z_c / (1.f + __expf(-z_c)));
            uc[(size_t)(rowbase + t0 + lane) * DI + d] = __float2bfloat16(g);
        }
        // (D) pack+write next BC tile; rotate per-lane scalars
        if (more) {
            const uint16_t* bp = (const uint16_t*)&Br;
            const uint16_t* cp = (const uint16_t*)&Cr;
#pragma unroll
            for (int j = 0; j < 8; ++j)
                BCt[cur ^ 1][sr][sc + j] = (uint32_t)bp[j] | ((uint32_t)cp[j] << 16);
            dtv_c = bs2f((short)dt_u);
            ucv   = bs2f((short)uc_u);
            dtu_c = dtv_c * ucv;
            ud_c  = ucv * Dd;
            z_c   = bs2f((short)z_u);
        }
        __syncthreads();
        cur ^= 1;
    }
}

extern "C" void kernel_launch(void* const* d_in, const int* in_sizes, int n_in,
                              void* d_out, int out_size, void* d_ws, size_t ws_size,
                              hipStream_t stream) {
    const float* x    = (const float*)d_in[0];
    const float* lnw  = (const float*)d_in[1];
    const float* lnb  = (const float*)d_in[2];
    const float* Win  = (const float*)d_in[3];
    const float* cw   = (const float*)d_in[4];
    const float* cb   = (const float*)d_in[5];
    const float* Wxp  = (const float*)d_in[6];
    const float* Wdt  = (const float*)d_in[7];
    const float* bdt  = (const float*)d_in[8];
    const float* Alog = (const float*)d_in[9];
    const float* Dp   = (const float*)d_in[10];
    const float* Wout = (const float*)d_in[11];
    float* out = (float*)d_out;           // reference output dtype = float32

    char* ws = (char*)d_ws;
    bf16* xn    = (bf16*)(ws + 0);                 // 8192x1024
    bf16* WtIn  = (bf16*)(ws + 16777216);          // 4096x1024
    bf16* WtXp  = (bf16*)(ws + 25165824);          // 256x2048 (zero-padded)
    bf16* WtDt  = (bf16*)(ws + 26214400);          // 2048x64
    bf16* WtOut = (bf16*)(ws + 26476544);          // 1024x2048
    bf16* uz    = (bf16*)(ws + 30670848);          // 8192x4096 (u | z)
    bf16* uc    = (bf16*)(ws + 97779712);          // 8192x2048 (u_c, then g in place)
    bf16* proj  = (bf16*)(ws + 131334144);         // 8192x192
    bf16* dtb   = (bf16*)(ws + 134479872);         // 8192x2048

    // weight transposes (Bt layouts, k-contiguous rows), f32 -> bf16
    transpose_pad<<<16384, 256, 0, stream>>>(Win,  WtIn,  1024, 10, 4096, 4096 * 1024);
    transpose_pad<<<2048,  256, 0, stream>>>(Wxp,  WtXp,  2048, 11, 192,  256 * 2048);
    transpose_pad<<<512,   256, 0, stream>>>(Wdt,  WtDt,  64,   6,  2048, 2048 * 64);
    transpose_pad<<<8192,  256, 0, stream>>>(Wout, WtOut, 2048, 11, 1024, 1024 * 2048);

    ln_kernel<<<2048, 256, 0, stream>>>(x, lnw, lnb, xn);
    gemm_bt<0><<<dim3(64, 32), 256, 0, stream>>>(xn, 1024, WtIn, 1024, 1024,
                                                 uz, nullptr, 4096, 4096, nullptr);
    conv_silu_kernel<<<8192, 256, 0, stream>>>(uz, cw, cb, uc);
    gemm_bt<0><<<dim3(64, 2), 256, 0, stream>>>(uc, 2048, WtXp, 2048, 2048,
                                                proj, nullptr, 192, 192, nullptr);
    gemm_bt<1><<<dim3(64, 16), 256, 0, stream>>>(proj, 192, WtDt, 64, 64,
                                                 dtb, nullptr, 2048, 2048, bdt);
    scan_kernel<<<2048, 256, 0, stream>>>(dtb, proj, uc, uz, Alog, Dp);
    gemm_bt<2><<<dim3(64, 8), 256, 0, stream>>>(uc, 2048, WtOut, 2048, 2048,
                                                nullptr, out, 1024, 1024, x);
}

// Round 12
// 670.598 us; speedup vs baseline: 2.6932x; 1.1176x over previous
//
#include <hip/hip_runtime.h>
#include <hip/hip_bf16.h>
#include <stdint.h>

#define SEQ   2048
#define DIM   1024
#define NST   64
#define DI    2048
#define DTR   64
#define ROWS  8192   // BATCH*SEQ
#define TS    32     // scan tile steps

typedef __hip_bfloat16 bf16;
typedef __attribute__((ext_vector_type(8))) short short8;   // 8 bf16 = 4 VGPRs
typedef __attribute__((ext_vector_type(4))) short bs4x;     // 4 bf16 = 2 VGPRs
typedef __attribute__((ext_vector_type(4))) float f32x4;
typedef __attribute__((ext_vector_type(2))) float f32x2;

typedef const __attribute__((address_space(1))) void gv_t;  // global
typedef __attribute__((address_space(3))) void lv_t;        // LDS

__device__ __forceinline__ float bs2f(short s) {
    return __uint_as_float(((uint32_t)(uint16_t)s) << 16);
}
__device__ __forceinline__ float lo16f(uint32_t u) {
    return __uint_as_float(u << 16);
}
__device__ __forceinline__ float hi16f(uint32_t u) {
    return __uint_as_float(u & 0xffff0000u);
}
__device__ __forceinline__ short f2bs(float f) {
    bf16 h = __float2bfloat16(f);
    return *(short*)&h;
}
__device__ __forceinline__ float b2f(bf16 v) { return __bfloat162float(v); }

// ------- transpose f32 -> bf16 with optional zero-pad: out[n][k] = in[k][n] --
__global__ __launch_bounds__(256) void transpose_pad(
    const float* __restrict__ in, bf16* __restrict__ out,
    int Kdim, int lgK, int Nin, int total)
{
    int idx = blockIdx.x * 256 + threadIdx.x;
    if (idx >= total) return;
    int n = idx >> lgK;
    int k = idx & (Kdim - 1);
    float v = (n < Nin) ? in[(size_t)k * Nin + n] : 0.f;
    out[idx] = __float2bfloat16(v);
}

// ---------------- LayerNorm: one wave per 1024-wide f32 row -> bf16 ---------
__global__ __launch_bounds__(256) void ln_kernel(
    const float* __restrict__ x, const float* __restrict__ w,
    const float* __restrict__ b, bf16* __restrict__ xn)
{
    int row  = blockIdx.x * 4 + (threadIdx.x >> 6);
    int lane = threadIdx.x & 63;
    const float4* xr = (const float4*)(x + (size_t)row * DIM);
    float4 v[4];
    float s = 0.f, s2 = 0.f;
#pragma unroll
    for (int q = 0; q < 4; ++q) {
        v[q] = xr[q * 64 + lane];
        s  += v[q].x + v[q].y + v[q].z + v[q].w;
        s2 += v[q].x*v[q].x + v[q].y*v[q].y + v[q].z*v[q].z + v[q].w*v[q].w;
    }
#pragma unroll
    for (int off = 32; off; off >>= 1) {
        s  += __shfl_xor(s, off);
        s2 += __shfl_xor(s2, off);
    }
    float mu  = s * (1.f / DIM);
    float var = s2 * (1.f / DIM) - mu * mu;
    float rs  = rsqrtf(var + 1e-5f);
    const float4* wp = (const float4*)w;
    const float4* bp = (const float4*)b;
#pragma unroll
    for (int q = 0; q < 4; ++q) {
        float4 wv = wp[q * 64 + lane];
        float4 bv = bp[q * 64 + lane];
        bs4x o;
        o[0] = f2bs((v[q].x - mu) * rs * wv.x + bv.x);
        o[1] = f2bs((v[q].y - mu) * rs * wv.y + bv.y);
        o[2] = f2bs((v[q].z - mu) * rs * wv.z + bv.z);
        o[3] = f2bs((v[q].w - mu) * rs * wv.w + bv.w);
        *(bs4x*)(xn + (size_t)row * DIM + (q * 64 + lane) * 4) = o;
    }
}

// ---------------- 128x128 BK=32 MFMA bf16 GEMM, Bt = [N][K] ----------------
template<int MODE>
__global__ __launch_bounds__(256) void gemm_bt(
    const bf16* __restrict__ A, int lda,
    const bf16* __restrict__ Bt, int ldb, int K,
    bf16* __restrict__ outp, float* __restrict__ outF, int ldo, int nvalid,
    const float* __restrict__ aux)
{
    __shared__ alignas(16) bf16 As[128 * 32];
    __shared__ alignas(16) bf16 Bs[128 * 32];
    const int tid = threadIdx.x;
    const int wid = tid >> 6, lane = tid & 63;
    const int m0 = blockIdx.x * 128, n0 = blockIdx.y * 128;
    const int wr = wid >> 1, wc = wid & 1;

    f32x4 acc[4][4];
#pragma unroll
    for (int i = 0; i < 4; ++i)
#pragma unroll
        for (int j = 0; j < 4; ++j) acc[i][j] = (f32x4){0.f, 0.f, 0.f, 0.f};

    const int srow = tid >> 2;           // 0..63
    const int scol = (tid & 3) * 8;      // 0,8,16,24
    const bf16* ga = A  + (size_t)(m0 + srow) * lda + scol;
    const bf16* gb = Bt + (size_t)(n0 + srow) * ldb + scol;
    char* lA0 = (char*)As + wid * 1024;
    char* lA1 = (char*)As + 4096 + wid * 1024;
    char* lB0 = (char*)Bs + wid * 1024;
    char* lB1 = (char*)Bs + 4096 + wid * 1024;

    const int frow = lane & 15;
    const int fk   = (lane >> 4) * 8;

    for (int k0 = 0; k0 < K; k0 += 32) {
        __builtin_amdgcn_global_load_lds((gv_t*)(ga + k0),                      (lv_t*)lA0, 16, 0, 0);
        __builtin_amdgcn_global_load_lds((gv_t*)(ga + (size_t)64 * lda + k0),   (lv_t*)lA1, 16, 0, 0);
        __builtin_amdgcn_global_load_lds((gv_t*)(gb + k0),                      (lv_t*)lB0, 16, 0, 0);
        __builtin_amdgcn_global_load_lds((gv_t*)(gb + (size_t)64 * ldb + k0),   (lv_t*)lB1, 16, 0, 0);
        __syncthreads();
        short8 af[4], bf_[4];
#pragma unroll
        for (int i = 0; i < 4; ++i) {
            af[i]  = *(const short8*)((const char*)As + ((wr*64 + i*16 + frow) * 32 + fk) * 2);
            bf_[i] = *(const short8*)((const char*)Bs + ((wc*64 + i*16 + frow) * 32 + fk) * 2);
        }
#pragma unroll
        for (int i = 0; i < 4; ++i)
#pragma unroll
            for (int j = 0; j < 4; ++j)
                acc[i][j] = __builtin_amdgcn_mfma_f32_16x16x32_bf16(af[i], bf_[j], acc[i][j], 0, 0, 0);
        __syncthreads();
    }

    const int erow = wr * 64 + (lane >> 4) * 4;
    const int ecol = wc * 64 + (lane & 15);
#pragma unroll
    for (int i = 0; i < 4; ++i)
#pragma unroll
        for (int j = 0; j < 4; ++j)
#pragma unroll
            for (int r = 0; r < 4; ++r) {
                int gr = m0 + erow + i * 16 + r;
                int gc = n0 + ecol + j * 16;
                float v = acc[i][j][r];
                if (MODE == 0) {
                    if (gc < nvalid) outp[(size_t)gr * ldo + gc] = __float2bfloat16(v);
                } else if (MODE == 1) {
                    v += aux[gc];
                    float sp = fmaxf(v, 0.f) + log1pf(__expf(-fabsf(v)));
                    outp[(size_t)gr * ldo + gc] = __float2bfloat16(sp);
                } else {
                    v += aux[(size_t)gr * ldo + gc];
                    outF[(size_t)gr * ldo + gc] = v;      // f32 final output
                }
            }
}

// ---------------- depthwise causal conv (DCONV=4) + SiLU -------------------
__global__ __launch_bounds__(256) void conv_silu_kernel(
    const bf16* __restrict__ uz, const float* __restrict__ cw,
    const float* __restrict__ cb, bf16* __restrict__ uc)
{
    int row = blockIdx.x;                 // 0..8191  (b*SEQ + t)
    int d8  = threadIdx.x * 8;            // channel group base
    int t   = row & (SEQ - 1);
    float accv[8];
    float4 cb0 = *(const float4*)(cb + d8);
    float4 cb1 = *(const float4*)(cb + d8 + 4);
    accv[0]=cb0.x; accv[1]=cb0.y; accv[2]=cb0.z; accv[3]=cb0.w;
    accv[4]=cb1.x; accv[5]=cb1.y; accv[6]=cb1.z; accv[7]=cb1.w;
    const float4* cw4 = (const float4*)cw;   // one float4 per channel (4 taps)
    float4 wj[8];
#pragma unroll
    for (int j = 0; j < 8; ++j) wj[j] = cw4[d8 + j];
#pragma unroll
    for (int k = 0; k < 4; ++k) {
        int tt = t + k - 3;
        if (tt < 0) continue;             // block-uniform predicate
        short8 uv = *(const short8*)(uz + (size_t)(row + k - 3) * 4096 + d8);
        float wk[8] = {((const float*)&wj[0])[k], ((const float*)&wj[1])[k],
                       ((const float*)&wj[2])[k], ((const float*)&wj[3])[k],
                       ((const float*)&wj[4])[k], ((const float*)&wj[5])[k],
                       ((const float*)&wj[6])[k], ((const float*)&wj[7])[k]};
#pragma unroll
        for (int j = 0; j < 8; ++j)
            accv[j] += bs2f(uv[j]) * wk[j];
    }
    short8 o;
#pragma unroll
    for (int j = 0; j < 8; ++j) {
        float v = accv[j];
        o[j] = f2bs(v / (1.f + __expf(-v)));
    }
    *(short8*)(uc + (size_t)row * DI + d8) = o;
}

// -------- selective scan v6: 2 states/lane, 2 d/wave, 8 d/block, TILE=32 ----
// Lane l = (ds = l>>5, j = l&31): channel d8+2*wid+ds, states {j, j+32}.
// BC tile shared by all 8 d (broadcast reads). P pre-summed f32 (stride 33).
// Reduce+gate use all 64 lanes (t = j, channel by ds). Double-buffered.
__global__ __launch_bounds__(256) void scan_kernel(
    const bf16* __restrict__ dt, const bf16* __restrict__ proj,
    bf16* __restrict__ uc, const bf16* __restrict__ uz,
    const float* __restrict__ A_log, const float* __restrict__ Dp)
{
    const int tid  = threadIdx.x;
    const int wid  = tid >> 6, lane = tid & 63;
    const int b    = blockIdx.x >> 8;          // 1024 blocks
    const int dg   = blockIdx.x & 255;
    const int d8   = dg * 8;
    const int ds   = lane >> 5;
    const int j    = lane & 31;
    const int dloc = wid * 2 + ds;
    const int d    = d8 + dloc;
    const int rowbase = b * SEQ;

    __shared__ alignas(8) uint2 BCp[2][TS][33];   // {pack(B[j],C[j]), pack(B[j+32],C[j+32])}
    __shared__ float2 DTD[2][8][TS];              // (dt, dt*u) per (dloc, t)
    __shared__ float2 GZ[2][8][TS];               // (u*D, z)
    __shared__ float  Pp[4][2][TS][33];           // pre-summed P per (wid, ds, t, j)

    const float L2E = 1.44269504f;
    const float a0 = -__expf(A_log[(size_t)d * NST + j]) * L2E;
    const float a1 = -__expf(A_log[(size_t)d * NST + j + 32]) * L2E;
    float h0 = 0.f, h1 = 0.f;

    // staging maps (256 threads)
    const int sr  = tid >> 3;                // 0..31 (t) for BC
    const int sj  = (tid & 7) * 4;           // j group of 4
    const int sdl = tid & 7;                 // dloc for DTD/GZ
    const int st  = tid >> 3;                // t for DTD/GZ
    const float Dd = Dp[d8 + sdl];
    const bf16* bsrc = proj + (size_t)(rowbase + sr) * 192 + DTR;

    uint2 Bl, Bh, Cl, Ch;
    uint16_t dt_u = 0, uc_u = 0, z_u = 0;

#define LOADG(T0)                                                              \
    {                                                                          \
        const bf16* p_ = bsrc + (size_t)(T0) * 192;                            \
        Bl = *(const uint2*)(p_ + sj);                                         \
        Bh = *(const uint2*)(p_ + 32 + sj);                                    \
        Cl = *(const uint2*)(p_ + 64 + sj);                                    \
        Ch = *(const uint2*)(p_ + 96 + sj);                                    \
        size_t r_ = (size_t)(rowbase + (T0) + st);                             \
        dt_u = *(const uint16_t*)&dt[r_ * DI + d8 + sdl];                      \
        uc_u = *(const uint16_t*)&uc[r_ * DI + d8 + sdl];                      \
        z_u  = *(const uint16_t*)&uz[r_ * 4096 + DI + d8 + sdl];               \
    }

#define STORE(BUF)                                                             \
    {                                                                          \
        BCp[BUF][sr][sj]     = (uint2){__builtin_amdgcn_perm(Cl.x, Bl.x, 0x05040100u), \
                                       __builtin_amdgcn_perm(Ch.x, Bh.x, 0x05040100u)}; \
        BCp[BUF][sr][sj + 1] = (uint2){__builtin_amdgcn_perm(Cl.x, Bl.x, 0x07060302u), \
                                       __builtin_amdgcn_perm(Ch.x, Bh.x, 0x07060302u)}; \
        BCp[BUF][sr][sj + 2] = (uint2){__builtin_amdgcn_perm(Cl.y, Bl.y, 0x05040100u), \
                                       __builtin_amdgcn_perm(Ch.y, Bh.y, 0x05040100u)}; \
        BCp[BUF][sr][sj + 3] = (uint2){__builtin_amdgcn_perm(Cl.y, Bl.y, 0x07060302u), \
                                       __builtin_amdgcn_perm(Ch.y, Bh.y, 0x07060302u)}; \
        float dtv_ = bs2f((short)dt_u);                                        \
        float uv_  = bs2f((short)uc_u);                                        \
        DTD[BUF][sdl][st] = make_float2(dtv_, dtv_ * uv_);                     \
        GZ[BUF][sdl][st]  = make_float2(uv_ * Dd, bs2f((short)z_u));           \
    }

    LOADG(0);
    STORE(0);
    __syncthreads();

    int cur = 0;
    for (int t0 = 0; t0 < SEQ; t0 += TS) {
        const bool more = (t0 + TS) < SEQ;
        if (more) LOADG(t0 + TS);

        // 32 steps x 2 states
        const uint2*  bcrow = &BCp[cur][0][j];
        const float2* ddrow = &DTD[cur][dloc][0];
        float* const  pwrow = &Pp[wid][ds][0][j];
#pragma unroll
        for (int tt = 0; tt < TS; ++tt) {
            uint2  bc = bcrow[tt * 33];
            float2 du = ddrow[tt];
            float B0 = lo16f(bc.x), C0 = hi16f(bc.x);
            float B1 = lo16f(bc.y), C1 = hi16f(bc.y);
            float dA0 = __builtin_amdgcn_exp2f(du.x * a0);
            float dA1 = __builtin_amdgcn_exp2f(du.x * a1);
            h0 = fmaf(h0, dA0, du.y * B0);
            h1 = fmaf(h1, dA1, du.y * B1);
            pwrow[tt * 33] = fmaf(h1, C1, h0 * C0);
        }
        __builtin_amdgcn_sched_barrier(0);

        // reduce over j (32 f32, conflict-free) + fused gate; all 64 lanes
        const float* pr = &Pp[wid][ds][j][0];
        float y = 0.f;
#pragma unroll
        for (int k = 0; k < 32; ++k) y += pr[k];
        float2 gz = GZ[cur][dloc][j];
        float g = (y + gz.x) * (gz.y / (1.f + __expf(-gz.y)));
        uc[(size_t)(rowbase + t0 + j) * DI + d] = __float2bfloat16(g);

        if (more) STORE(cur ^ 1);
        __syncthreads();
        cur ^= 1;
    }
#undef LOADG
#undef STORE
}

extern "C" void kernel_launch(void* const* d_in, const int* in_sizes, int n_in,
                              void* d_out, int out_size, void* d_ws, size_t ws_size,
                              hipStream_t stream) {
    const float* x    = (const float*)d_in[0];
    const float* lnw  = (const float*)d_in[1];
    const float* lnb  = (const float*)d_in[2];
    const float* Win  = (const float*)d_in[3];
    const float* cw   = (const float*)d_in[4];
    const float* cb   = (const float*)d_in[5];
    const float* Wxp  = (const float*)d_in[6];
    const float* Wdt  = (const float*)d_in[7];
    const float* bdt  = (const float*)d_in[8];
    const float* Alog = (const float*)d_in[9];
    const float* Dp   = (const float*)d_in[10];
    const float* Wout = (const float*)d_in[11];
    float* out = (float*)d_out;           // reference output dtype = float32

    char* ws = (char*)d_ws;
    bf16* xn    = (bf16*)(ws + 0);                 // 8192x1024
    bf16* WtIn  = (bf16*)(ws + 16777216);          // 4096x1024
    bf16* WtXp  = (bf16*)(ws + 25165824);          // 256x2048 (zero-padded)
    bf16* WtDt  = (bf16*)(ws + 26214400);          // 2048x64
    bf16* WtOut = (bf16*)(ws + 26476544);          // 1024x2048
    bf16* uz    = (bf16*)(ws + 30670848);          // 8192x4096 (u | z)
    bf16* uc    = (bf16*)(ws + 97779712);          // 8192x2048 (u_c, then g in place)
    bf16* proj  = (bf16*)(ws + 131334144);         // 8192x192
    bf16* dtb   = (bf16*)(ws + 134479872);         // 8192x2048

    // weight transposes (Bt layouts, k-contiguous rows), f32 -> bf16
    transpose_pad<<<16384, 256, 0, stream>>>(Win,  WtIn,  1024, 10, 4096, 4096 * 1024);
    transpose_pad<<<2048,  256, 0, stream>>>(Wxp,  WtXp,  2048, 11, 192,  256 * 2048);
    transpose_pad<<<512,   256, 0, stream>>>(Wdt,  WtDt,  64,   6,  2048, 2048 * 64);
    transpose_pad<<<8192,  256, 0, stream>>>(Wout, WtOut, 2048, 11, 1024, 1024 * 2048);

    ln_kernel<<<2048, 256, 0, stream>>>(x, lnw, lnb, xn);
    gemm_bt<0><<<dim3(64, 32), 256, 0, stream>>>(xn, 1024, WtIn, 1024, 1024,
                                                 uz, nullptr, 4096, 4096, nullptr);
    conv_silu_kernel<<<8192, 256, 0, stream>>>(uz, cw, cb, uc);
    gemm_bt<0><<<dim3(64, 2), 256, 0, stream>>>(uc, 2048, WtXp, 2048, 2048,
                                                proj, nullptr, 192, 192, nullptr);
    gemm_bt<1><<<dim3(64, 16), 256, 0, stream>>>(proj, 192, WtDt, 64, 64,
                                                 dtb, nullptr, 2048, 2048, bdt);
    scan_kernel<<<1024, 256, 0, stream>>>(dtb, proj, uc, uz, Alog, Dp);
    gemm_bt<2><<<dim3(64, 8), 256, 0, stream>>>(uc, 2048, WtOut, 2048, 2048,
                                                nullptr, out, 1024, 1024, x);
}